// Round 5
// baseline (727.570 us; speedup 1.0000x reference)
//
#include <hip/hip_runtime.h>
#include <float.h>
#include <math.h>

#define TOKENS 8192
#define EXPERTS 256
#define HIDDEN 7168
#define TOPK 8
#define TOPKG 4

#define BM 64
#define BN 64
#define BK 32
#define NKT (HIDDEN / BK)   // 224

#define TAU_E 6.0e-6f   // expert-rank margin threshold (score space), ~10 sigma
#define TAU_G 1.2e-5f   // group-selection margin threshold, ~14 sigma
#define MAXFB 1024

// ---- ws layout (bytes) ----
// [0, 8388608)   f32 logits [8192][256]  (later overlaid by f64 lgs[1024][256] = 2MB)
// [8388608)      counter (int)
// [8388864)      flagged-token list (MAXFB ints)
// [8454144)      Wh fragment-order bf16 [4 nb][224 kt][4 slot][64 lane][8] (3.67MB)
// [12124160)     Wl same (3.67MB)
#define CNT_B   8388608
#define LIST_B  8388864
#define WH_B    8454144
#define WL_B    12124160

typedef __attribute__((ext_vector_type(8))) short bf16x8;
typedef __attribute__((ext_vector_type(4))) float f32x4;

__device__ inline ushort bf16_rne(float x) {
    uint u = __float_as_uint(x);
    return (ushort)((u + 0x7FFFu + ((u >> 16) & 1u)) >> 16);
}
__device__ inline float bf16_tof(ushort h) { return __uint_as_float((uint)h << 16); }

// packed f32->bf16 RNE: dst.lo16 = cvt(lo), dst.hi16 = cvt(hi)
#define CVTPK(lo, hi) ({ uint r_; asm("v_cvt_pk_bf16_f32 %0, %1, %2" : "=v"(r_) : "v"(lo), "v"(hi)); r_; })
__device__ inline float lo16f(uint u) { return __uint_as_float(u << 16); }
__device__ inline float hi16f(uint u) { return __uint_as_float(u & 0xFFFF0000u); }

// Pre-split W into bf16 hi/lo in per-lane MFMA fragment order:
// wh[((nb*NKT + kt)*4 + wn*2 + n)*512 + lane*8 + j] =
//   bf16( W[nb*64 + wn*32 + n*16 + (lane&15)][kt*32 + (lane>>4)*8 + j] )
__global__ __launch_bounds__(256) void split_w(const float* __restrict__ W,
                                               ushort* __restrict__ wh,
                                               ushort* __restrict__ wl,
                                               int* __restrict__ cnt) {
    if (blockIdx.x == 0 && threadIdx.x == 0) *cnt = 0;
    const int tau  = blockIdx.x * 256 + threadIdx.x;   // [0, 4*224*2048)
    const int j    = tau & 7;
    const int lane = (tau >> 3) & 63;
    const int ns   = (tau >> 9) & 3;
    const int idx2 = tau >> 11;
    const int nb   = idx2 / NKT;
    const int kt   = idx2 - nb * NKT;
    const int col  = nb * 64 + (ns >> 1) * 32 + (ns & 1) * 16 + (lane & 15);
    const int k    = kt * 32 + (lane >> 4) * 8 + j;
    const float w  = W[(size_t)col * HIDDEN + k];
    const ushort h = bf16_rne(w);
    const ushort l = bf16_rne(w - bf16_tof(h));
    wh[tau] = h;
    wl[tau] = l;
}

// ---------------- bf16-split MFMA GEMM ----------------
// 512 blocks (2/CU), 4 waves, wave tile 32x32. A staged in LDS (double-buffered,
// 2-deep register prefetch, cvt_pk split); W fragments loaded directly from the
// pre-split L2-resident image (1-deep prefetch). 3 passes AhWh + AlWh + AhWl.
__global__ __launch_bounds__(256, 2) void logits_mfma(const float* __restrict__ A,
                                                      const ushort* __restrict__ wh,
                                                      const ushort* __restrict__ wl,
                                                      float* __restrict__ out) {
    __shared__ ushort Ah[2][BM * BK];   // 4KB per buf
    __shared__ ushort Al[2][BM * BK];

    const int b  = blockIdx.x;
    const int nb = (b & 7) >> 1;                  // XCD-pinned N-block
    const int mb = ((b >> 3) << 1) | (b & 1);     // 0..127
    const int row0 = mb * BM, col0 = nb * BN;

    const int t    = threadIdx.x;
    const int lane = t & 63;
    const int wid  = t >> 6;
    const int wm   = wid >> 1, wn = wid & 1;

    // A staging map: thread t -> row r0 = t>>2, k-octet q = t&3
    const int q  = t & 3;
    const int r0 = t >> 2;
    const float* Ap = A + (size_t)(row0 + r0) * HIDDEN + q * 8;
    const int idxS = r0 * BK + ((q ^ ((r0 >> 1) & 3)) << 3);

    // fragment read addresses
    const int fr = lane & 15, fg = lane >> 4;
    const int ra0 = wm * 32 + fr;
    const int idxA0 = ra0 * BK + (((fg) ^ ((ra0 >> 1) & 3)) << 3);
    const int idxA1 = idxA0 + 16 * BK;

    // W fragment base (per-lane)
    const ushort* whT = wh + (size_t)nb * NKT * 2048;
    const ushort* wlT = wl + (size_t)nb * NKT * 2048;
    const size_t wofs = (size_t)(wn * 2) * 512 + lane * 8;

    f32x4 acc[2][2];
    #pragma unroll
    for (int m = 0; m < 2; ++m)
        #pragma unroll
        for (int n = 0; n < 2; ++n) acc[m][n] = (f32x4)0.f;

    float4 arA0, arA1, arB0, arB1;
    bf16x8 wAh0, wAh1, wAl0, wAl1, wBh0, wBh1, wBl0, wBl1;

    #define STAGE(BB, A0, A1) do {                                             \
        uint h0 = CVTPK(A0.x, A0.y), h1 = CVTPK(A0.z, A0.w);                   \
        uint h2 = CVTPK(A1.x, A1.y), h3 = CVTPK(A1.z, A1.w);                   \
        float r0_ = A0.x - lo16f(h0), r1_ = A0.y - hi16f(h0);                  \
        float r2_ = A0.z - lo16f(h1), r3_ = A0.w - hi16f(h1);                  \
        float r4_ = A1.x - lo16f(h2), r5_ = A1.y - hi16f(h2);                  \
        float r6_ = A1.z - lo16f(h3), r7_ = A1.w - hi16f(h3);                  \
        uint l0 = CVTPK(r0_, r1_), l1 = CVTPK(r2_, r3_);                       \
        uint l2 = CVTPK(r4_, r5_), l3 = CVTPK(r6_, r7_);                       \
        *(uint4*)&Ah[BB][idxS] = make_uint4(h0, h1, h2, h3);                   \
        *(uint4*)&Al[BB][idxS] = make_uint4(l0, l1, l2, l3);                   \
    } while (0)

    #define MF __builtin_amdgcn_mfma_f32_16x16x32_bf16

    #define ITER(KT, BB, AR, CW, NW) do {                                      \
        __syncthreads();                                                       \
        const bf16x8 afh0 = *(const bf16x8*)&Ah[BB][idxA0];                    \
        const bf16x8 afl0 = *(const bf16x8*)&Al[BB][idxA0];                    \
        const bf16x8 afh1 = *(const bf16x8*)&Ah[BB][idxA1];                    \
        const bf16x8 afl1 = *(const bf16x8*)&Al[BB][idxA1];                    \
        { const int ktn = ((KT) + 1 < NKT) ? (KT) + 1 : NKT - 1;               \
          const size_t wo = (size_t)ktn * 2048 + wofs;                         \
          NW##h0 = *(const bf16x8*)(whT + wo);                                 \
          NW##h1 = *(const bf16x8*)(whT + wo + 512);                           \
          NW##l0 = *(const bf16x8*)(wlT + wo);                                 \
          NW##l1 = *(const bf16x8*)(wlT + wo + 512); }                         \
        STAGE((BB) ^ 1, AR##0, AR##1);                                         \
        { const int kta = (((KT) + 3 < NKT) ? (KT) + 3 : NKT - 1) * BK;        \
          AR##0 = *(const float4*)(Ap + kta);                                  \
          AR##1 = *(const float4*)(Ap + kta + 4); }                            \
        acc[0][0] = MF(afh0, CW##h0, acc[0][0], 0, 0, 0);                      \
        acc[0][0] = MF(afl0, CW##h0, acc[0][0], 0, 0, 0);                      \
        acc[0][0] = MF(afh0, CW##l0, acc[0][0], 0, 0, 0);                      \
        acc[0][1] = MF(afh0, CW##h1, acc[0][1], 0, 0, 0);                      \
        acc[0][1] = MF(afl0, CW##h1, acc[0][1], 0, 0, 0);                      \
        acc[0][1] = MF(afh0, CW##l1, acc[0][1], 0, 0, 0);                      \
        acc[1][0] = MF(afh1, CW##h0, acc[1][0], 0, 0, 0);                      \
        acc[1][0] = MF(afl1, CW##h0, acc[1][0], 0, 0, 0);                      \
        acc[1][0] = MF(afh1, CW##l0, acc[1][0], 0, 0, 0);                      \
        acc[1][1] = MF(afh1, CW##h1, acc[1][1], 0, 0, 0);                      \
        acc[1][1] = MF(afl1, CW##h1, acc[1][1], 0, 0, 0);                      \
        acc[1][1] = MF(afh1, CW##l1, acc[1][1], 0, 0, 0);                      \
    } while (0)

    // prologue
    arA0 = *(const float4*)(Ap);       arA1 = *(const float4*)(Ap + 4);        // tile 0
    STAGE(0, arA0, arA1);
    arA0 = *(const float4*)(Ap + BK);  arA1 = *(const float4*)(Ap + BK + 4);   // tile 1
    arB0 = *(const float4*)(Ap + 2*BK); arB1 = *(const float4*)(Ap + 2*BK + 4);// tile 2
    wAh0 = *(const bf16x8*)(whT + wofs);
    wAh1 = *(const bf16x8*)(whT + wofs + 512);
    wAl0 = *(const bf16x8*)(wlT + wofs);
    wAl1 = *(const bf16x8*)(wlT + wofs + 512);

    for (int kt2 = 0; kt2 < NKT; kt2 += 2) {
        ITER(kt2,     0, arA, wA, wB);
        ITER(kt2 + 1, 1, arB, wB, wA);
    }

    // epilogue: C/D layout col=lane&15, row=(lane>>4)*4+reg
    #pragma unroll
    for (int m = 0; m < 2; ++m)
        #pragma unroll
        for (int n = 0; n < 2; ++n)
            #pragma unroll
            for (int g = 0; g < 4; ++g)
                out[(size_t)(row0 + wm * 32 + m * 16 + (fg << 2) + g) * EXPERTS +
                    (col0 + wn * 32 + n * 16 + fr)] = acc[m][n][g];
    #undef ITER
    #undef STAGE
    #undef MF
}

// ---------------- fast route with decision margins ----------------
__global__ __launch_bounds__(256) void route_margin(const float* __restrict__ logits,
                                                    const float* __restrict__ bias,
                                                    float* __restrict__ out,
                                                    int* __restrict__ cnt,
                                                    int* __restrict__ list) {
    const int lane = threadIdx.x & 63;
    const int t    = blockIdx.x * 4 + (threadIdx.x >> 6);

    const float4 lg = *(const float4*)(logits + (size_t)t * EXPERTS + (lane << 2));
    const float4 bz = *(const float4*)(bias + (lane << 2));

    const float s0 = 1.f / (1.f + expf(-lg.x));
    const float s1 = 1.f / (1.f + expf(-lg.y));
    const float s2 = 1.f / (1.f + expf(-lg.z));
    const float s3 = 1.f / (1.f + expf(-lg.w));
    const float b0 = s0 + bz.x, b1 = s1 + bz.y, b2 = s2 + bz.z, b3 = s3 + bz.w;

    float hi01 = fmaxf(b0, b1), lo01 = fminf(b0, b1);
    float hi23 = fmaxf(b2, b3), lo23 = fminf(b2, b3);
    float a0v = fmaxf(hi01, hi23);
    float a1v = fmaxf(fminf(hi01, hi23), fmaxf(lo01, lo23));
    #pragma unroll
    for (int off = 1; off < 8; off <<= 1) {
        float o0 = __shfl_xor(a0v, off);
        float o1 = __shfl_xor(a1v, off);
        float n0 = fmaxf(a0v, o0);
        float n1 = fmaxf(fminf(a0v, o0), fmaxf(a1v, o1));
        a0v = n0; a1v = n1;
    }
    const float gscore = a0v + a1v;

    float gsc[8];
    #pragma unroll
    for (int g = 0; g < 8; ++g) gsc[g] = __shfl(gscore, g << 3);

    const int g0 = lane >> 3;
    int myrank = 0;
    float v4 = -1e30f, v5 = -1e30f;
    #pragma unroll
    for (int h = 0; h < 8; ++h) {
        int rk = 0;
        #pragma unroll
        for (int h2 = 0; h2 < 8; ++h2)
            rk += ((gsc[h2] > gsc[h]) || (gsc[h2] == gsc[h] && h2 < h)) ? 1 : 0;
        if (h == g0) myrank = rk;
        if (rk == TOPKG - 1) v4 = gsc[h];
        if (rk == TOPKG)     v5 = gsc[h];
    }
    const bool sel = (myrank < TOPKG);
    const float margin_g = v4 - v5;

    float m0 = sel ? b0 : 0.f;
    float m1 = sel ? b1 : 0.f;
    float m2 = sel ? b2 : 0.f;
    float m3 = sel ? b3 : 0.f;

    float sum = 0.f;
    int myidx = 0; float mysc = 0.f;
    float prev = 0.f, mine = 1e30f;
    #pragma unroll
    for (int rr = 0; rr < TOPK + 1; ++rr) {
        float bv = m0; int bj = 0;
        if (m1 > bv) { bv = m1; bj = 1; }
        if (m2 > bv) { bv = m2; bj = 2; }
        if (m3 > bv) { bv = m3; bj = 3; }
        float bsc = (bj == 0) ? s0 : (bj == 1) ? s1 : (bj == 2) ? s2 : s3;
        int bidx = (lane << 2) | bj;
        #pragma unroll
        for (int off = 1; off < 64; off <<= 1) {
            float ov  = __shfl_xor(bv, off);
            int   oi  = __shfl_xor(bidx, off);
            float osc = __shfl_xor(bsc, off);
            if (ov > bv || (ov == bv && oi < bidx)) { bv = ov; bidx = oi; bsc = osc; }
        }
        if (rr) mine = fminf(mine, prev - bv);
        prev = bv;
        if (rr < TOPK) {
            sum += bsc;
            if (lane == rr) { myidx = bidx; mysc = bsc; }
            if ((bidx >> 2) == lane) {
                const int sl = bidx & 3;
                if      (sl == 0) m0 = -FLT_MAX;
                else if (sl == 1) m1 = -FLT_MAX;
                else if (sl == 2) m2 = -FLT_MAX;
                else              m3 = -FLT_MAX;
            }
        }
    }

    const bool fb = (margin_g < TAU_G) || (mine < TAU_E);
    if (fb) {
        if (lane == 0) { int p = atomicAdd(cnt, 1); if (p < MAXFB) list[p] = t; }
    } else if (lane < TOPK) {
        const size_t base = (size_t)t * TOPK + lane;
        out[base] = (float)myidx;
        out[(size_t)TOKENS * TOPK + base] = mysc / (sum + 1e-20f) * 2.5f;
    }
}

// ---------------- f1: exact f64 logits for flagged tokens (batched) ----------------
// Block = 4 flagged tokens; 1024 threads = 256 experts x 4 K-quarters.
// W read once per block; A addresses wave-uniform.
__global__ __launch_bounds__(1024) void fallback_logits(const float* __restrict__ A,
                                                        const float* __restrict__ W,
                                                        const int* __restrict__ cnt,
                                                        const int* __restrict__ list,
                                                        double* __restrict__ lgs) {
    __shared__ double part[4][4][EXPERTS];   // [kq][t][e] = 32KB
    const int n = min(*cnt, MAXFB);
    const int base = blockIdx.x * 4;
    if (base >= n) return;
    const int e  = threadIdx.x & 255;
    const int kq = threadIdx.x >> 8;

    int tok[4];
    #pragma unroll
    for (int i = 0; i < 4; ++i) tok[i] = (base + i < n) ? list[base + i] : list[base];

    const int k0 = kq * (HIDDEN / 4);
    const float* wr = W + (size_t)e * HIDDEN + k0;
    const float* a0p = A + (size_t)tok[0] * HIDDEN + k0;
    const float* a1p = A + (size_t)tok[1] * HIDDEN + k0;
    const float* a2p = A + (size_t)tok[2] * HIDDEN + k0;
    const float* a3p = A + (size_t)tok[3] * HIDDEN + k0;

    double ac0 = 0, ac1 = 0, ac2 = 0, ac3 = 0;
    for (int k = 0; k < HIDDEN / 4; k += 4) {
        const float4 w4 = *(const float4*)(wr + k);
        const float4 x0 = *(const float4*)(a0p + k);
        const float4 x1 = *(const float4*)(a1p + k);
        const float4 x2 = *(const float4*)(a2p + k);
        const float4 x3 = *(const float4*)(a3p + k);
        ac0 = fma((double)x0.x, (double)w4.x, ac0); ac0 = fma((double)x0.y, (double)w4.y, ac0);
        ac0 = fma((double)x0.z, (double)w4.z, ac0); ac0 = fma((double)x0.w, (double)w4.w, ac0);
        ac1 = fma((double)x1.x, (double)w4.x, ac1); ac1 = fma((double)x1.y, (double)w4.y, ac1);
        ac1 = fma((double)x1.z, (double)w4.z, ac1); ac1 = fma((double)x1.w, (double)w4.w, ac1);
        ac2 = fma((double)x2.x, (double)w4.x, ac2); ac2 = fma((double)x2.y, (double)w4.y, ac2);
        ac2 = fma((double)x2.z, (double)w4.z, ac2); ac2 = fma((double)x2.w, (double)w4.w, ac2);
        ac3 = fma((double)x3.x, (double)w4.x, ac3); ac3 = fma((double)x3.y, (double)w4.y, ac3);
        ac3 = fma((double)x3.z, (double)w4.z, ac3); ac3 = fma((double)x3.w, (double)w4.w, ac3);
    }
    part[kq][0][e] = ac0; part[kq][1][e] = ac1;
    part[kq][2][e] = ac2; part[kq][3][e] = ac3;
    __syncthreads();
    if (kq == 0) {
        #pragma unroll
        for (int i = 0; i < 4; ++i)
            if (base + i < n)
                lgs[(size_t)(base + i) * EXPERTS + e] =
                    ((part[0][i][e] + part[1][i][e]) + part[2][i][e]) + part[3][i][e];
    }
}

// ---------------- f2: exact f64 route for flagged tokens ----------------
__global__ __launch_bounds__(256) void fallback_route(const double* __restrict__ lgs,
                                                      const float* __restrict__ bias,
                                                      const int* __restrict__ cnt,
                                                      const int* __restrict__ list,
                                                      float* __restrict__ out) {
    const int n  = min(*cnt, MAXFB);
    const int ti = blockIdx.x * 4 + (threadIdx.x >> 6);
    if (ti >= n) return;
    const int lane = threadIdx.x & 63;
    const int t = list[ti];

    const double l0 = lgs[(size_t)ti * EXPERTS + (lane << 2)];
    const double l1 = lgs[(size_t)ti * EXPERTS + (lane << 2) + 1];
    const double l2 = lgs[(size_t)ti * EXPERTS + (lane << 2) + 2];
    const double l3 = lgs[(size_t)ti * EXPERTS + (lane << 2) + 3];
    const float4 bzf = *(const float4*)(bias + (lane << 2));

    const double s0 = 1.0 / (1.0 + exp(-l0));
    const double s1 = 1.0 / (1.0 + exp(-l1));
    const double s2 = 1.0 / (1.0 + exp(-l2));
    const double s3 = 1.0 / (1.0 + exp(-l3));
    const double b0 = s0 + (double)bzf.x, b1 = s1 + (double)bzf.y;
    const double b2 = s2 + (double)bzf.z, b3 = s3 + (double)bzf.w;

    double hi01 = fmax(b0, b1), lo01 = fmin(b0, b1);
    double hi23 = fmax(b2, b3), lo23 = fmin(b2, b3);
    double a0v = fmax(hi01, hi23);
    double a1v = fmax(fmin(hi01, hi23), fmax(lo01, lo23));
    #pragma unroll
    for (int off = 1; off < 8; off <<= 1) {
        double o0 = __shfl_xor(a0v, off);
        double o1 = __shfl_xor(a1v, off);
        double n0 = fmax(a0v, o0);
        double n1 = fmax(fmin(a0v, o0), fmax(a1v, o1));
        a0v = n0; a1v = n1;
    }
    const double gscore = a0v + a1v;
    double gsc[8];
    #pragma unroll
    for (int g = 0; g < 8; ++g) gsc[g] = __shfl(gscore, g << 3);
    const int g0 = lane >> 3;
    int rank = 0;
    #pragma unroll
    for (int h = 0; h < 8; ++h)
        rank += ((gsc[h] > gscore) || (gsc[h] == gscore && h < g0)) ? 1 : 0;
    const bool sel = (rank < TOPKG);

    double m0 = sel ? b0 : 0.0;
    double m1 = sel ? b1 : 0.0;
    double m2 = sel ? b2 : 0.0;
    double m3 = sel ? b3 : 0.0;

    double sum = 0.0;
    int myidx = 0; double mysc = 0.0;
    #pragma unroll
    for (int rr = 0; rr < TOPK; ++rr) {
        double bv = m0; int bj = 0;
        if (m1 > bv) { bv = m1; bj = 1; }
        if (m2 > bv) { bv = m2; bj = 2; }
        if (m3 > bv) { bv = m3; bj = 3; }
        double bsc = (bj == 0) ? s0 : (bj == 1) ? s1 : (bj == 2) ? s2 : s3;
        int bidx = (lane << 2) | bj;
        #pragma unroll
        for (int off = 1; off < 64; off <<= 1) {
            double ov  = __shfl_xor(bv, off);
            int    oi  = __shfl_xor(bidx, off);
            double osc = __shfl_xor(bsc, off);
            if (ov > bv || (ov == bv && oi < bidx)) { bv = ov; bidx = oi; bsc = osc; }
        }
        sum += bsc;
        if (lane == rr) { myidx = bidx; mysc = bsc; }
        if ((bidx >> 2) == lane) {
            const int sl = bidx & 3;
            if      (sl == 0) m0 = -DBL_MAX;
            else if (sl == 1) m1 = -DBL_MAX;
            else if (sl == 2) m2 = -DBL_MAX;
            else              m3 = -DBL_MAX;
        }
    }
    if (lane < TOPK) {
        const size_t base = (size_t)t * TOPK + lane;
        out[base] = (float)myidx;
        out[(size_t)TOKENS * TOPK + base] = (float)(mysc / (sum + 1e-20) * 2.5);
    }
}

extern "C" void kernel_launch(void* const* d_in, const int* in_sizes, int n_in,
                              void* d_out, int out_size, void* d_ws, size_t ws_size,
                              hipStream_t stream) {
    const float* hs   = (const float*)d_in[0];
    const float* wt   = (const float*)d_in[1];
    const float* bias = (const float*)d_in[2];
    float* out = (float*)d_out;

    char* ws = (char*)d_ws;
    float*  logits = (float*)ws;
    double* lgs64  = (double*)ws;           // overlays logits (f1 runs after route)
    int*    cnt    = (int*)(ws + CNT_B);
    int*    list   = (int*)(ws + LIST_B);
    ushort* wsh    = (ushort*)(ws + WH_B);
    ushort* wsl    = (ushort*)(ws + WL_B);

    split_w<<<(4 * NKT * 2048) / 256, 256, 0, stream>>>(wt, wsh, wsl, cnt);
    logits_mfma<<<(TOKENS / BM) * (EXPERTS / BN), 256, 0, stream>>>(hs, wsh, wsl, logits);
    route_margin<<<TOKENS / 4, 256, 0, stream>>>(logits, bias, out, cnt, list);
    fallback_logits<<<MAXFB / 4, 1024, 0, stream>>>(hs, wt, cnt, list, lgs64);
    fallback_route<<<MAXFB / 4, 256, 0, stream>>>(lgs64, bias, cnt, list, out);
}

// Round 6
// 512.477 us; speedup vs baseline: 1.4197x; 1.4197x over previous
//
#include <hip/hip_runtime.h>
#include <float.h>
#include <math.h>

#define TOKENS 8192
#define EXPERTS 256
#define HIDDEN 7168
#define TOPK 8
#define TOPKG 4

#define BM 64
#define BN 64
#define BK 32
#define NKT (HIDDEN / BK)   // 224

#define TAU_E 6.0e-6f   // expert-rank margin threshold (score space)
#define TAU_G 1.2e-5f   // group-selection margin threshold
#define MAXFB 1024

// ---- ws layout (bytes) ----
// [0, 8388608)   f32 logits [8192][256]  (later overlaid by f64 lgs[MAXFB][256] = 2MB)
// [8388608)      counter (int)
// [8388864)      flagged-token list (MAXFB ints)
// [8454144)      Wh fragment-order bf16 [4 nb][224 kt][4 slot][64 lane][8] (3.67MB)
// [12124160)     Wl same (3.67MB)
#define CNT_B   8388608
#define LIST_B  8388864
#define WH_B    8454144
#define WL_B    12124160

typedef __attribute__((ext_vector_type(8))) short bf16x8;
typedef __attribute__((ext_vector_type(4))) float f32x4;

__device__ inline ushort bf16_rne(float x) {
    uint u = __float_as_uint(x);
    return (ushort)((u + 0x7FFFu + ((u >> 16) & 1u)) >> 16);
}
__device__ inline float bf16_tof(ushort h) { return __uint_as_float((uint)h << 16); }

// packed f32->bf16 RNE: dst.lo16 = cvt(lo), dst.hi16 = cvt(hi)
#define CVTPK(lo, hi) ({ uint r_; asm("v_cvt_pk_bf16_f32 %0, %1, %2" : "=v"(r_) : "v"(lo), "v"(hi)); r_; })
__device__ inline float lo16f(uint u) { return __uint_as_float(u << 16); }
__device__ inline float hi16f(uint u) { return __uint_as_float(u & 0xFFFF0000u); }

// Pre-split W into bf16 hi/lo in per-lane MFMA fragment order:
// wh[((nb*NKT + kt)*4 + slot)*512 + lane*8 + j] =
//   bf16( W[nb*64 + (slot>>1)*32 + (slot&1)*16 + (lane&15)][kt*32 + (lane>>4)*8 + j] )
__global__ __launch_bounds__(256) void split_w(const float* __restrict__ W,
                                               ushort* __restrict__ wh,
                                               ushort* __restrict__ wl,
                                               int* __restrict__ cnt) {
    if (blockIdx.x == 0 && threadIdx.x == 0) *cnt = 0;
    const int tau  = blockIdx.x * 256 + threadIdx.x;   // [0, 4*224*2048)
    const int j    = tau & 7;
    const int lane = (tau >> 3) & 63;
    const int ns   = (tau >> 9) & 3;
    const int idx2 = tau >> 11;
    const int nb   = idx2 / NKT;
    const int kt   = idx2 - nb * NKT;
    const int col  = nb * 64 + (ns >> 1) * 32 + (ns & 1) * 16 + (lane & 15);
    const int k    = kt * 32 + (lane >> 4) * 8 + j;
    const float w  = W[(size_t)col * HIDDEN + k];
    const ushort h = bf16_rne(w);
    const ushort l = bf16_rne(w - bf16_tof(h));
    wh[tau] = h;
    wl[tau] = l;
}

// ---------------- bf16-split MFMA GEMM (v3: W through LDS) ----------------
// 512 blocks (3/CU), 4 waves, wave tile 32x32. A and W both double-buffered in
// LDS; W staged from the pre-split fragment-order image (16B/thread coalesced,
// shared by all waves). 3 passes AhWh + AlWh + AhWl, fp32 MFMA accumulation.
__global__ __launch_bounds__(256, 3) void logits_mfma(const float* __restrict__ A,
                                                      const ushort* __restrict__ wh,
                                                      const ushort* __restrict__ wl,
                                                      float* __restrict__ out) {
    __shared__ ushort Ah[2][BM * BK];   // 4KB per buf
    __shared__ ushort Al[2][BM * BK];
    __shared__ ushort Wh[2][BN * BK];   // 4KB per buf
    __shared__ ushort Wl[2][BN * BK];

    const int b  = blockIdx.x;
    const int nb = (b & 7) >> 1;                  // XCD-pinned N-block
    const int mb = ((b >> 3) << 1) | (b & 1);     // 0..127
    const int row0 = mb * BM, col0 = nb * BN;

    const int t    = threadIdx.x;
    const int lane = t & 63;
    const int wid  = t >> 6;
    const int wm   = wid >> 1, wn = wid & 1;

    // A staging map: thread t -> row r0 = t>>2, k-octet q = t&3
    const int q  = t & 3;
    const int r0 = t >> 2;
    const float* Ap = A + (size_t)(row0 + r0) * HIDDEN + q * 8;
    const int idxS = r0 * BK + ((q ^ ((r0 >> 1) & 3)) << 3);

    // fragment read addresses
    const int fr = lane & 15, fg = lane >> 4;
    const int ra0 = wm * 32 + fr;
    const int idxA0 = ra0 * BK + ((fg ^ ((ra0 >> 1) & 3)) << 3);
    const int idxA1 = idxA0 + 16 * BK;
    const int idxW0 = (wn * 2) * 512 + lane * 8;
    const int idxW1 = idxW0 + 512;

    const ushort* whT = wh + (size_t)nb * NKT * 2048;
    const ushort* wlT = wl + (size_t)nb * NKT * 2048;

    f32x4 acc[2][2];
    #pragma unroll
    for (int m = 0; m < 2; ++m)
        #pragma unroll
        for (int n = 0; n < 2; ++n) acc[m][n] = (f32x4)0.f;

    float4 ar0, ar1;    // A staging regs (tile kt+1 during iter kt)
    uint4  wrh, wrl;    // W staging regs

    #define STAGE_A(BB) do {                                                   \
        uint h0 = CVTPK(ar0.x, ar0.y), h1 = CVTPK(ar0.z, ar0.w);               \
        uint h2 = CVTPK(ar1.x, ar1.y), h3 = CVTPK(ar1.z, ar1.w);               \
        float r0_ = ar0.x - lo16f(h0), r1_ = ar0.y - hi16f(h0);                \
        float r2_ = ar0.z - lo16f(h1), r3_ = ar0.w - hi16f(h1);                \
        float r4_ = ar1.x - lo16f(h2), r5_ = ar1.y - hi16f(h2);                \
        float r6_ = ar1.z - lo16f(h3), r7_ = ar1.w - hi16f(h3);                \
        uint l0 = CVTPK(r0_, r1_), l1 = CVTPK(r2_, r3_);                       \
        uint l2 = CVTPK(r4_, r5_), l3 = CVTPK(r6_, r7_);                       \
        *(uint4*)&Ah[BB][idxS] = make_uint4(h0, h1, h2, h3);                   \
        *(uint4*)&Al[BB][idxS] = make_uint4(l0, l1, l2, l3);                   \
    } while (0)

    #define MF __builtin_amdgcn_mfma_f32_16x16x32_bf16

    #define ITER(KT, BB) do {                                                  \
        __syncthreads();                                                       \
        const bf16x8 afh0 = *(const bf16x8*)&Ah[BB][idxA0];                    \
        const bf16x8 afl0 = *(const bf16x8*)&Al[BB][idxA0];                    \
        const bf16x8 afh1 = *(const bf16x8*)&Ah[BB][idxA1];                    \
        const bf16x8 afl1 = *(const bf16x8*)&Al[BB][idxA1];                    \
        const bf16x8 wfh0 = *(const bf16x8*)&Wh[BB][idxW0];                    \
        const bf16x8 wfh1 = *(const bf16x8*)&Wh[BB][idxW1];                    \
        const bf16x8 wfl0 = *(const bf16x8*)&Wl[BB][idxW0];                    \
        const bf16x8 wfl1 = *(const bf16x8*)&Wl[BB][idxW1];                    \
        if ((KT) + 1 < NKT) {                                                  \
            STAGE_A((BB) ^ 1);                                                 \
            *(uint4*)&Wh[(BB) ^ 1][t * 8] = wrh;                               \
            *(uint4*)&Wl[(BB) ^ 1][t * 8] = wrl;                               \
        }                                                                      \
        { const int kta = (((KT) + 2 < NKT) ? (KT) + 2 : NKT - 1) * BK;        \
          ar0 = *(const float4*)(Ap + kta);                                    \
          ar1 = *(const float4*)(Ap + kta + 4);                                \
          const size_t wo = (size_t)(((KT) + 2 < NKT) ? (KT) + 2 : NKT - 1) * 2048 + t * 8; \
          wrh = *(const uint4*)(whT + wo);                                     \
          wrl = *(const uint4*)(wlT + wo); }                                   \
        acc[0][0] = MF(afh0, wfh0, acc[0][0], 0, 0, 0);                        \
        acc[0][0] = MF(afl0, wfh0, acc[0][0], 0, 0, 0);                        \
        acc[0][0] = MF(afh0, wfl0, acc[0][0], 0, 0, 0);                        \
        acc[0][1] = MF(afh0, wfh1, acc[0][1], 0, 0, 0);                        \
        acc[0][1] = MF(afl0, wfh1, acc[0][1], 0, 0, 0);                        \
        acc[0][1] = MF(afh0, wfl1, acc[0][1], 0, 0, 0);                        \
        acc[1][0] = MF(afh1, wfh0, acc[1][0], 0, 0, 0);                        \
        acc[1][0] = MF(afl1, wfh0, acc[1][0], 0, 0, 0);                        \
        acc[1][0] = MF(afh1, wfl0, acc[1][0], 0, 0, 0);                        \
        acc[1][1] = MF(afh1, wfh1, acc[1][1], 0, 0, 0);                        \
        acc[1][1] = MF(afl1, wfh1, acc[1][1], 0, 0, 0);                        \
        acc[1][1] = MF(afh1, wfl1, acc[1][1], 0, 0, 0);                        \
    } while (0)

    // prologue: stage kt=0, preload regs for kt=1
    ar0 = *(const float4*)(Ap);
    ar1 = *(const float4*)(Ap + 4);
    wrh = *(const uint4*)(whT + t * 8);
    wrl = *(const uint4*)(wlT + t * 8);
    STAGE_A(0);
    *(uint4*)&Wh[0][t * 8] = wrh;
    *(uint4*)&Wl[0][t * 8] = wrl;
    ar0 = *(const float4*)(Ap + BK);
    ar1 = *(const float4*)(Ap + BK + 4);
    wrh = *(const uint4*)(whT + 2048 + t * 8);
    wrl = *(const uint4*)(wlT + 2048 + t * 8);

    for (int kt2 = 0; kt2 < NKT; kt2 += 2) {
        ITER(kt2, 0);
        ITER(kt2 + 1, 1);
    }

    // epilogue: C/D layout col=lane&15, row=(lane>>4)*4+reg
    #pragma unroll
    for (int m = 0; m < 2; ++m)
        #pragma unroll
        for (int n = 0; n < 2; ++n)
            #pragma unroll
            for (int g = 0; g < 4; ++g)
                out[(size_t)(row0 + wm * 32 + m * 16 + (fg << 2) + g) * EXPERTS +
                    (col0 + wn * 32 + n * 16 + fr)] = acc[m][n][g];
    #undef ITER
    #undef STAGE_A
    #undef MF
}

// ---------------- fast route with decision margins ----------------
__global__ __launch_bounds__(256) void route_margin(const float* __restrict__ logits,
                                                    const float* __restrict__ bias,
                                                    float* __restrict__ out,
                                                    int* __restrict__ cnt,
                                                    int* __restrict__ list) {
    const int lane = threadIdx.x & 63;
    const int t    = blockIdx.x * 4 + (threadIdx.x >> 6);

    const float4 lg = *(const float4*)(logits + (size_t)t * EXPERTS + (lane << 2));
    const float4 bz = *(const float4*)(bias + (lane << 2));

    const float s0 = 1.f / (1.f + expf(-lg.x));
    const float s1 = 1.f / (1.f + expf(-lg.y));
    const float s2 = 1.f / (1.f + expf(-lg.z));
    const float s3 = 1.f / (1.f + expf(-lg.w));
    const float b0 = s0 + bz.x, b1 = s1 + bz.y, b2 = s2 + bz.z, b3 = s3 + bz.w;

    float hi01 = fmaxf(b0, b1), lo01 = fminf(b0, b1);
    float hi23 = fmaxf(b2, b3), lo23 = fminf(b2, b3);
    float a0v = fmaxf(hi01, hi23);
    float a1v = fmaxf(fminf(hi01, hi23), fmaxf(lo01, lo23));
    #pragma unroll
    for (int off = 1; off < 8; off <<= 1) {
        float o0 = __shfl_xor(a0v, off);
        float o1 = __shfl_xor(a1v, off);
        float n0 = fmaxf(a0v, o0);
        float n1 = fmaxf(fminf(a0v, o0), fmaxf(a1v, o1));
        a0v = n0; a1v = n1;
    }
    const float gscore = a0v + a1v;

    float gsc[8];
    #pragma unroll
    for (int g = 0; g < 8; ++g) gsc[g] = __shfl(gscore, g << 3);

    const int g0 = lane >> 3;
    int myrank = 0;
    float v4 = -1e30f, v5 = -1e30f;
    #pragma unroll
    for (int h = 0; h < 8; ++h) {
        int rk = 0;
        #pragma unroll
        for (int h2 = 0; h2 < 8; ++h2)
            rk += ((gsc[h2] > gsc[h]) || (gsc[h2] == gsc[h] && h2 < h)) ? 1 : 0;
        if (h == g0) myrank = rk;
        if (rk == TOPKG - 1) v4 = gsc[h];
        if (rk == TOPKG)     v5 = gsc[h];
    }
    const bool sel = (myrank < TOPKG);
    const float margin_g = v4 - v5;

    float m0 = sel ? b0 : 0.f;
    float m1 = sel ? b1 : 0.f;
    float m2 = sel ? b2 : 0.f;
    float m3 = sel ? b3 : 0.f;

    float sum = 0.f;
    int myidx = 0; float mysc = 0.f;
    float prev = 0.f, mine = 1e30f;
    #pragma unroll
    for (int rr = 0; rr < TOPK + 1; ++rr) {
        float bv = m0; int bj = 0;
        if (m1 > bv) { bv = m1; bj = 1; }
        if (m2 > bv) { bv = m2; bj = 2; }
        if (m3 > bv) { bv = m3; bj = 3; }
        float bsc = (bj == 0) ? s0 : (bj == 1) ? s1 : (bj == 2) ? s2 : s3;
        int bidx = (lane << 2) | bj;
        #pragma unroll
        for (int off = 1; off < 64; off <<= 1) {
            float ov  = __shfl_xor(bv, off);
            int   oi  = __shfl_xor(bidx, off);
            float osc = __shfl_xor(bsc, off);
            if (ov > bv || (ov == bv && oi < bidx)) { bv = ov; bidx = oi; bsc = osc; }
        }
        if (rr) mine = fminf(mine, prev - bv);
        prev = bv;
        if (rr < TOPK) {
            sum += bsc;
            if (lane == rr) { myidx = bidx; mysc = bsc; }
            if ((bidx >> 2) == lane) {
                const int sl = bidx & 3;
                if      (sl == 0) m0 = -FLT_MAX;
                else if (sl == 1) m1 = -FLT_MAX;
                else if (sl == 2) m2 = -FLT_MAX;
                else              m3 = -FLT_MAX;
            }
        }
    }

    const bool fb = (margin_g < TAU_G) || (mine < TAU_E);
    if (fb) {
        if (lane == 0) { int p = atomicAdd(cnt, 1); if (p < MAXFB) list[p] = t; }
    } else if (lane < TOPK) {
        const size_t base = (size_t)t * TOPK + lane;
        out[base] = (float)myidx;
        out[(size_t)TOKENS * TOPK + base] = mysc / (sum + 1e-20f) * 2.5f;
    }
}

// ---------------- f1: exact f64 logits for flagged tokens (coalesced) ----------------
// Block = 2 flagged tokens staged in LDS; each wave owns one expert at a time:
// lane l reads W[e][it*256 + 4l .. +3] (fully coalesced float4), f64 FMA,
// then a 6-step f64 shuffle reduction. No uncoalesced W access.
__global__ __launch_bounds__(256) void fallback_logits(const float* __restrict__ A,
                                                       const float* __restrict__ W,
                                                       const int* __restrict__ cnt,
                                                       const int* __restrict__ list,
                                                       double* __restrict__ lgs) {
    __shared__ float As[2][HIDDEN];   // 56KB
    const int n = min(*cnt, MAXFB);
    const int base = blockIdx.x * 2;
    if (base >= n) return;
    const int tid = threadIdx.x;
    const int t0 = list[base];
    const int t1 = (base + 1 < n) ? list[base + 1] : t0;

    const float4* a0g = (const float4*)(A + (size_t)t0 * HIDDEN);
    const float4* a1g = (const float4*)(A + (size_t)t1 * HIDDEN);
    for (int i = tid; i < HIDDEN / 4; i += 256) {
        ((float4*)As[0])[i] = a0g[i];
        ((float4*)As[1])[i] = a1g[i];
    }
    __syncthreads();

    const int lane = tid & 63, wv = tid >> 6;
    for (int ei = 0; ei < 64; ++ei) {
        const int e = wv * 64 + ei;
        const float* wr = W + (size_t)e * HIDDEN;
        double ac0 = 0.0, ac1 = 0.0;
        #pragma unroll 4
        for (int it = 0; it < HIDDEN / 256; ++it) {   // 28 iterations
            const int k = it * 256 + (lane << 2);
            const float4 w4 = *(const float4*)(wr + k);
            const float4 x0 = *(const float4*)&As[0][k];
            const float4 x1 = *(const float4*)&As[1][k];
            ac0 = fma((double)x0.x, (double)w4.x, ac0);
            ac0 = fma((double)x0.y, (double)w4.y, ac0);
            ac0 = fma((double)x0.z, (double)w4.z, ac0);
            ac0 = fma((double)x0.w, (double)w4.w, ac0);
            ac1 = fma((double)x1.x, (double)w4.x, ac1);
            ac1 = fma((double)x1.y, (double)w4.y, ac1);
            ac1 = fma((double)x1.z, (double)w4.z, ac1);
            ac1 = fma((double)x1.w, (double)w4.w, ac1);
        }
        #pragma unroll
        for (int off = 32; off; off >>= 1) {
            ac0 += __shfl_xor(ac0, off);
            ac1 += __shfl_xor(ac1, off);
        }
        if (lane == 0) {
            lgs[(size_t)base * EXPERTS + e] = ac0;
            if (base + 1 < n) lgs[(size_t)(base + 1) * EXPERTS + e] = ac1;
        }
    }
}

// ---------------- f2: exact f64 route for flagged tokens ----------------
__global__ __launch_bounds__(256) void fallback_route(const double* __restrict__ lgs,
                                                      const float* __restrict__ bias,
                                                      const int* __restrict__ cnt,
                                                      const int* __restrict__ list,
                                                      float* __restrict__ out) {
    const int n  = min(*cnt, MAXFB);
    const int ti = blockIdx.x * 4 + (threadIdx.x >> 6);
    if (ti >= n) return;
    const int lane = threadIdx.x & 63;
    const int t = list[ti];

    const double l0 = lgs[(size_t)ti * EXPERTS + (lane << 2)];
    const double l1 = lgs[(size_t)ti * EXPERTS + (lane << 2) + 1];
    const double l2 = lgs[(size_t)ti * EXPERTS + (lane << 2) + 2];
    const double l3 = lgs[(size_t)ti * EXPERTS + (lane << 2) + 3];
    const float4 bzf = *(const float4*)(bias + (lane << 2));

    const double s0 = 1.0 / (1.0 + exp(-l0));
    const double s1 = 1.0 / (1.0 + exp(-l1));
    const double s2 = 1.0 / (1.0 + exp(-l2));
    const double s3 = 1.0 / (1.0 + exp(-l3));
    const double b0 = s0 + (double)bzf.x, b1 = s1 + (double)bzf.y;
    const double b2 = s2 + (double)bzf.z, b3 = s3 + (double)bzf.w;

    double hi01 = fmax(b0, b1), lo01 = fmin(b0, b1);
    double hi23 = fmax(b2, b3), lo23 = fmin(b2, b3);
    double a0v = fmax(hi01, hi23);
    double a1v = fmax(fmin(hi01, hi23), fmax(lo01, lo23));
    #pragma unroll
    for (int off = 1; off < 8; off <<= 1) {
        double o0 = __shfl_xor(a0v, off);
        double o1 = __shfl_xor(a1v, off);
        double n0 = fmax(a0v, o0);
        double n1 = fmax(fmin(a0v, o0), fmax(a1v, o1));
        a0v = n0; a1v = n1;
    }
    const double gscore = a0v + a1v;
    double gsc[8];
    #pragma unroll
    for (int g = 0; g < 8; ++g) gsc[g] = __shfl(gscore, g << 3);
    const int g0 = lane >> 3;
    int rank = 0;
    #pragma unroll
    for (int h = 0; h < 8; ++h)
        rank += ((gsc[h] > gscore) || (gsc[h] == gscore && h < g0)) ? 1 : 0;
    const bool sel = (rank < TOPKG);

    double m0 = sel ? b0 : 0.0;
    double m1 = sel ? b1 : 0.0;
    double m2 = sel ? b2 : 0.0;
    double m3 = sel ? b3 : 0.0;

    double sum = 0.0;
    int myidx = 0; double mysc = 0.0;
    #pragma unroll
    for (int rr = 0; rr < TOPK; ++rr) {
        double bv = m0; int bj = 0;
        if (m1 > bv) { bv = m1; bj = 1; }
        if (m2 > bv) { bv = m2; bj = 2; }
        if (m3 > bv) { bv = m3; bj = 3; }
        double bsc = (bj == 0) ? s0 : (bj == 1) ? s1 : (bj == 2) ? s2 : s3;
        int bidx = (lane << 2) | bj;
        #pragma unroll
        for (int off = 1; off < 64; off <<= 1) {
            double ov  = __shfl_xor(bv, off);
            int    oi  = __shfl_xor(bidx, off);
            double osc = __shfl_xor(bsc, off);
            if (ov > bv || (ov == bv && oi < bidx)) { bv = ov; bidx = oi; bsc = osc; }
        }
        sum += bsc;
        if (lane == rr) { myidx = bidx; mysc = bsc; }
        if ((bidx >> 2) == lane) {
            const int sl = bidx & 3;
            if      (sl == 0) m0 = -DBL_MAX;
            else if (sl == 1) m1 = -DBL_MAX;
            else if (sl == 2) m2 = -DBL_MAX;
            else              m3 = -DBL_MAX;
        }
    }
    if (lane < TOPK) {
        const size_t base = (size_t)t * TOPK + lane;
        out[base] = (float)myidx;
        out[(size_t)TOKENS * TOPK + base] = (float)(mysc / (sum + 1e-20) * 2.5);
    }
}

extern "C" void kernel_launch(void* const* d_in, const int* in_sizes, int n_in,
                              void* d_out, int out_size, void* d_ws, size_t ws_size,
                              hipStream_t stream) {
    const float* hs   = (const float*)d_in[0];
    const float* wt   = (const float*)d_in[1];
    const float* bias = (const float*)d_in[2];
    float* out = (float*)d_out;

    char* ws = (char*)d_ws;
    float*  logits = (float*)ws;
    double* lgs64  = (double*)ws;           // overlays logits (f1 runs after route)
    int*    cnt    = (int*)(ws + CNT_B);
    int*    list   = (int*)(ws + LIST_B);
    ushort* wsh    = (ushort*)(ws + WH_B);
    ushort* wsl    = (ushort*)(ws + WL_B);

    split_w<<<(4 * NKT * 2048) / 256, 256, 0, stream>>>(wt, wsh, wsl, cnt);
    logits_mfma<<<(TOKENS / BM) * (EXPERTS / BN), 256, 0, stream>>>(hs, wsh, wsl, logits);
    route_margin<<<TOKENS / 4, 256, 0, stream>>>(logits, bias, out, cnt, list);
    fallback_logits<<<MAXFB / 2, 256, 0, stream>>>(hs, wt, cnt, list, lgs64);
    fallback_route<<<MAXFB / 4, 256, 0, stream>>>(lgs64, bias, cnt, list, out);
}

// Round 7
// 397.178 us; speedup vs baseline: 1.8318x; 1.2903x over previous
//
#include <hip/hip_runtime.h>
#include <float.h>
#include <math.h>

#define TOKENS 8192
#define EXPERTS 256
#define HIDDEN 7168
#define TOPK 8
#define TOPKG 4

#define BM 128
#define BN 128
#define BK 32
#define KSPLIT 2
#define KHALF (HIDDEN / KSPLIT)   // 3584
#define NKT2 (KHALF / BK)         // 112 k-steps per split-K block
#define NKT16 (HIDDEN / 16)       // 448

#define TAU_E 6.0e-6f
#define TAU_G 1.2e-5f
#define MAXFB 1024

// ---- ws layouts (bytes) ----
// partial path (ws >= 24248320):
//   P0 [0,8M) | P1 [8M,16M) | cnt 16777216 | list 16777472 | WH 16908288 | WL 20578304
// atomic path:
//   LG [0,8M) | cnt 8388608 | list 8388864 | WH 8519680 | WL 12189696
#define WIMG_HALF 1835008   // ushorts per half (2 nb * 448 kt16 * 4 cg * 512)

typedef __attribute__((ext_vector_type(8))) short bf16x8;
typedef __attribute__((ext_vector_type(16))) float f32x16;

__device__ inline ushort bf16_rne(float x) {
    uint u = __float_as_uint(x);
    return (ushort)((u + 0x7FFFu + ((u >> 16) & 1u)) >> 16);
}
__device__ inline float bf16_tof(ushort h) { return __uint_as_float((uint)h << 16); }

#define CVTPK(lo, hi) ({ uint r_; asm("v_cvt_pk_bf16_f32 %0, %1, %2" : "=v"(r_) : "v"(lo), "v"(hi)); r_; })
__device__ inline float lo16f(uint u) { return __uint_as_float(u << 16); }
__device__ inline float hi16f(uint u) { return __uint_as_float(u & 0xFFFF0000u); }

// Pre-split W into bf16 hi/lo, 32x32-MFMA per-lane fragment order:
// wh[((nb*448+kt16)*4+cg)*512 + lane*8 + j] =
//   bf16( W[nb*128 + cg*32 + (lane&31)][kt16*16 + (lane>>5)*8 + j] )
__global__ __launch_bounds__(256) void split_w(const float* __restrict__ W,
                                               ushort* __restrict__ wh,
                                               ushort* __restrict__ wl,
                                               int* __restrict__ cnt) {
    if (blockIdx.x == 0 && threadIdx.x == 0) *cnt = 0;
    const int tau  = blockIdx.x * 256 + threadIdx.x;   // [0, 1835008)
    const int j    = tau & 7;
    const int lane = (tau >> 3) & 63;
    const int cg   = (tau >> 9) & 3;
    const int idx2 = tau >> 11;
    const int nb   = idx2 / 448;
    const int kt16 = idx2 - nb * 448;
    const int col  = nb * 128 + cg * 32 + (lane & 31);
    const int k    = kt16 * 16 + (lane >> 5) * 8 + j;
    const float w  = W[(size_t)col * HIDDEN + k];
    const ushort h = bf16_rne(w);
    const ushort l = bf16_rne(w - bf16_tof(h));
    wh[tau] = h;
    wl[tau] = l;
}

// ---------------- bf16-split 32x32 MFMA GEMM, split-K=2 ----------------
// Grid 256 (1 block/CU): ks = b>>7; nb = (b>>3)&1; mb = (b&7)|((b>>4)<<3)
// so partner blocks (nb=0/1) sit 8 apart -> same XCD -> A L2-shared.
// 4 waves, wave tile 64x64 (Mr=Nr=2). A via LDS dbuf; W frags direct from L2.
template <bool ATOMIC>
__global__ __launch_bounds__(256, 1) void logits_mfma(const float* __restrict__ A,
                                                      const ushort* __restrict__ wh,
                                                      const ushort* __restrict__ wl,
                                                      float* __restrict__ dst) {
    __shared__ ushort Ah[2][BM * BK];   // 8KB per buf
    __shared__ ushort Al[2][BM * BK];

    const int b  = blockIdx.x;
    const int ks = b >> 7;
    const int r7 = b & 127;
    const int nb = (r7 >> 3) & 1;
    const int mb = (r7 & 7) | ((r7 >> 4) << 3);
    const int row0 = mb * BM, col0 = nb * BN;

    const int t = threadIdx.x, lane = t & 63, wid = t >> 6;
    const int wm = wid >> 1, wn = wid & 1;

    // A staging: thread t -> row sr=t>>1, k-16-half sko=t&1 (16 floats)
    const int sr = t >> 1, sko = t & 1;
    const float* Ap = A + (size_t)(row0 + sr) * HIDDEN + (size_t)ks * KHALF + sko * 16;
    const int sswz  = ((sr >> 1) ^ (sr >> 3)) & 3;
    const int sidx0 = sr * 32 + (((sko * 2)     ^ sswz) << 3);
    const int sidx1 = sr * 32 + (((sko * 2 + 1) ^ sswz) << 3);

    // A fragment read indices [mi][kh]
    int fidx[2][2];
    #pragma unroll
    for (int mi = 0; mi < 2; ++mi) {
        const int r = wm * 64 + mi * 32 + (lane & 31);
        const int swz = ((r >> 1) ^ (r >> 3)) & 3;
        #pragma unroll
        for (int kh = 0; kh < 2; ++kh) {
            const int o = kh * 2 + (lane >> 5);
            fidx[mi][kh] = r * 32 + ((o ^ swz) << 3);
        }
    }

    const ushort* whT = wh + (size_t)nb * 917504;
    const ushort* wlT = wl + (size_t)nb * 917504;
    const int wbase = (wn * 2) * 512 + lane * 8;

    f32x16 acc[2][2];
    #pragma unroll
    for (int mi = 0; mi < 2; ++mi)
        #pragma unroll
        for (int n = 0; n < 2; ++n) acc[mi][n] = (f32x16)0.f;

    float4 aA0, aA1, aA2, aA3, aB0, aB1, aB2, aB3;
    bf16x8 wAh[2][2], wAl[2][2], wBh[2][2], wBl[2][2];   // [n][kh]

    #define WLOAD(DH, DL, KT) do {                                             \
        const size_t wo = ((size_t)(ks * 224 + (KT) * 2) * 4) * 512 + wbase;   \
        DH[0][0] = *(const bf16x8*)(whT + wo);                                 \
        DH[1][0] = *(const bf16x8*)(whT + wo + 512);                           \
        DH[0][1] = *(const bf16x8*)(whT + wo + 2048);                          \
        DH[1][1] = *(const bf16x8*)(whT + wo + 2560);                          \
        DL[0][0] = *(const bf16x8*)(wlT + wo);                                 \
        DL[1][0] = *(const bf16x8*)(wlT + wo + 512);                           \
        DL[0][1] = *(const bf16x8*)(wlT + wo + 2048);                          \
        DL[1][1] = *(const bf16x8*)(wlT + wo + 2560);                          \
    } while (0)

    #define STAGE(BB, R0, R1, R2, R3) do {                                     \
        uint h0 = CVTPK(R0.x, R0.y), h1 = CVTPK(R0.z, R0.w);                   \
        uint h2 = CVTPK(R1.x, R1.y), h3 = CVTPK(R1.z, R1.w);                   \
        uint h4 = CVTPK(R2.x, R2.y), h5 = CVTPK(R2.z, R2.w);                   \
        uint h6 = CVTPK(R3.x, R3.y), h7 = CVTPK(R3.z, R3.w);                   \
        float q0 = R0.x - lo16f(h0), q1 = R0.y - hi16f(h0);                    \
        float q2 = R0.z - lo16f(h1), q3 = R0.w - hi16f(h1);                    \
        float q4 = R1.x - lo16f(h2), q5 = R1.y - hi16f(h2);                    \
        float q6 = R1.z - lo16f(h3), q7 = R1.w - hi16f(h3);                    \
        float q8 = R2.x - lo16f(h4), q9 = R2.y - hi16f(h4);                    \
        float qa = R2.z - lo16f(h5), qb = R2.w - hi16f(h5);                    \
        float qc = R3.x - lo16f(h6), qd = R3.y - hi16f(h6);                    \
        float qe = R3.z - lo16f(h7), qf = R3.w - hi16f(h7);                    \
        uint l0 = CVTPK(q0, q1), l1 = CVTPK(q2, q3);                           \
        uint l2 = CVTPK(q4, q5), l3 = CVTPK(q6, q7);                           \
        uint l4 = CVTPK(q8, q9), l5 = CVTPK(qa, qb);                           \
        uint l6 = CVTPK(qc, qd), l7 = CVTPK(qe, qf);                           \
        *(uint4*)&Ah[BB][sidx0] = make_uint4(h0, h1, h2, h3);                  \
        *(uint4*)&Ah[BB][sidx1] = make_uint4(h4, h5, h6, h7);                  \
        *(uint4*)&Al[BB][sidx0] = make_uint4(l0, l1, l2, l3);                  \
        *(uint4*)&Al[BB][sidx1] = make_uint4(l4, l5, l6, l7);                  \
    } while (0)

    #define ALOAD(R0, R1, R2, R3, KT) do {                                     \
        const int ka = ((KT) < NKT2 ? (KT) : NKT2 - 1) * BK;                   \
        R0 = *(const float4*)(Ap + ka);                                        \
        R1 = *(const float4*)(Ap + ka + 4);                                    \
        R2 = *(const float4*)(Ap + ka + 8);                                    \
        R3 = *(const float4*)(Ap + ka + 12);                                   \
    } while (0)

    #define MF __builtin_amdgcn_mfma_f32_32x32x16_bf16

    #define ITER(KT, BB, X0, X1, X2, X3, WXH, WXL, WYH, WYL) do {              \
        __syncthreads();                                                       \
        bf16x8 afh[2][2], afl[2][2];                                           \
        afh[0][0] = *(const bf16x8*)&Ah[BB][fidx[0][0]];                       \
        afh[0][1] = *(const bf16x8*)&Ah[BB][fidx[0][1]];                       \
        afh[1][0] = *(const bf16x8*)&Ah[BB][fidx[1][0]];                       \
        afh[1][1] = *(const bf16x8*)&Ah[BB][fidx[1][1]];                       \
        afl[0][0] = *(const bf16x8*)&Al[BB][fidx[0][0]];                       \
        afl[0][1] = *(const bf16x8*)&Al[BB][fidx[0][1]];                       \
        afl[1][0] = *(const bf16x8*)&Al[BB][fidx[1][0]];                       \
        afl[1][1] = *(const bf16x8*)&Al[BB][fidx[1][1]];                       \
        STAGE((BB) ^ 1, X0, X1, X2, X3);                                       \
        ALOAD(X0, X1, X2, X3, (KT) + 3);                                       \
        WLOAD(WYH, WYL, ((KT) + 1 < NKT2 ? (KT) + 1 : NKT2 - 1));              \
        acc[0][0] = MF(afh[0][0], WXH[0][0], acc[0][0], 0, 0, 0);              \
        acc[0][0] = MF(afl[0][0], WXH[0][0], acc[0][0], 0, 0, 0);              \
        acc[0][0] = MF(afh[0][0], WXL[0][0], acc[0][0], 0, 0, 0);              \
        acc[0][1] = MF(afh[0][0], WXH[1][0], acc[0][1], 0, 0, 0);              \
        acc[0][1] = MF(afl[0][0], WXH[1][0], acc[0][1], 0, 0, 0);              \
        acc[0][1] = MF(afh[0][0], WXL[1][0], acc[0][1], 0, 0, 0);              \
        acc[1][0] = MF(afh[1][0], WXH[0][0], acc[1][0], 0, 0, 0);              \
        acc[1][0] = MF(afl[1][0], WXH[0][0], acc[1][0], 0, 0, 0);              \
        acc[1][0] = MF(afh[1][0], WXL[0][0], acc[1][0], 0, 0, 0);              \
        acc[1][1] = MF(afh[1][0], WXH[1][0], acc[1][1], 0, 0, 0);              \
        acc[1][1] = MF(afl[1][0], WXH[1][0], acc[1][1], 0, 0, 0);              \
        acc[1][1] = MF(afh[1][0], WXL[1][0], acc[1][1], 0, 0, 0);              \
        acc[0][0] = MF(afh[0][1], WXH[0][1], acc[0][0], 0, 0, 0);              \
        acc[0][0] = MF(afl[0][1], WXH[0][1], acc[0][0], 0, 0, 0);              \
        acc[0][0] = MF(afh[0][1], WXL[0][1], acc[0][0], 0, 0, 0);              \
        acc[0][1] = MF(afh[0][1], WXH[1][1], acc[0][1], 0, 0, 0);              \
        acc[0][1] = MF(afl[0][1], WXH[1][1], acc[0][1], 0, 0, 0);              \
        acc[0][1] = MF(afh[0][1], WXL[1][1], acc[0][1], 0, 0, 0);              \
        acc[1][0] = MF(afh[1][1], WXH[0][1], acc[1][0], 0, 0, 0);              \
        acc[1][0] = MF(afl[1][1], WXH[0][1], acc[1][0], 0, 0, 0);              \
        acc[1][0] = MF(afh[1][1], WXL[0][1], acc[1][0], 0, 0, 0);              \
        acc[1][1] = MF(afh[1][1], WXH[1][1], acc[1][1], 0, 0, 0);              \
        acc[1][1] = MF(afl[1][1], WXH[1][1], acc[1][1], 0, 0, 0);              \
        acc[1][1] = MF(afh[1][1], WXL[1][1], acc[1][1], 0, 0, 0);              \
    } while (0)

    // prologue
    ALOAD(aA0, aA1, aA2, aA3, 0);
    STAGE(0, aA0, aA1, aA2, aA3);
    ALOAD(aA0, aA1, aA2, aA3, 1);
    ALOAD(aB0, aB1, aB2, aB3, 2);
    WLOAD(wAh, wAl, 0);

    for (int kt2 = 0; kt2 < NKT2; kt2 += 2) {
        ITER(kt2,     0, aA0, aA1, aA2, aA3, wAh, wAl, wBh, wBl);
        ITER(kt2 + 1, 1, aB0, aB1, aB2, aB3, wBh, wBl, wAh, wAl);
    }

    // epilogue: C/D col=lane&31, row=(g&3)+8*(g>>2)+4*(lane>>5)  [m74/m101]
    float* o = ATOMIC ? dst : dst + (size_t)ks * TOKENS * EXPERTS;
    #pragma unroll
    for (int mi = 0; mi < 2; ++mi)
        #pragma unroll
        for (int n = 0; n < 2; ++n)
            #pragma unroll
            for (int g = 0; g < 16; ++g) {
                const int row = row0 + wm * 64 + mi * 32 + (g & 3) + ((g >> 2) << 3) + ((lane >> 5) << 2);
                const int col = col0 + wn * 64 + n * 32 + (lane & 31);
                const size_t idx = (size_t)row * EXPERTS + col;
                if (ATOMIC) atomicAdd(o + idx, acc[mi][n][g]);
                else        o[idx] = acc[mi][n][g];
            }
    #undef ITER
    #undef MF
    #undef ALOAD
    #undef STAGE
    #undef WLOAD
}

// ---------------- fast route with decision margins ----------------
template <bool TWO>
__global__ __launch_bounds__(256) void route_margin(const float* __restrict__ p0,
                                                    const float* __restrict__ bias,
                                                    float* __restrict__ out,
                                                    int* __restrict__ cnt,
                                                    int* __restrict__ list) {
    const int lane = threadIdx.x & 63;
    const int t    = blockIdx.x * 4 + (threadIdx.x >> 6);

    float4 lg = *(const float4*)(p0 + (size_t)t * EXPERTS + (lane << 2));
    if (TWO) {
        const float4 lg2 = *(const float4*)(p0 + (size_t)TOKENS * EXPERTS +
                                            (size_t)t * EXPERTS + (lane << 2));
        lg.x += lg2.x; lg.y += lg2.y; lg.z += lg2.z; lg.w += lg2.w;
    }
    const float4 bz = *(const float4*)(bias + (lane << 2));

    const float s0 = 1.f / (1.f + expf(-lg.x));
    const float s1 = 1.f / (1.f + expf(-lg.y));
    const float s2 = 1.f / (1.f + expf(-lg.z));
    const float s3 = 1.f / (1.f + expf(-lg.w));
    const float b0 = s0 + bz.x, b1 = s1 + bz.y, b2 = s2 + bz.z, b3 = s3 + bz.w;

    float hi01 = fmaxf(b0, b1), lo01 = fminf(b0, b1);
    float hi23 = fmaxf(b2, b3), lo23 = fminf(b2, b3);
    float a0v = fmaxf(hi01, hi23);
    float a1v = fmaxf(fminf(hi01, hi23), fmaxf(lo01, lo23));
    #pragma unroll
    for (int off = 1; off < 8; off <<= 1) {
        float o0 = __shfl_xor(a0v, off);
        float o1 = __shfl_xor(a1v, off);
        float n0 = fmaxf(a0v, o0);
        float n1 = fmaxf(fminf(a0v, o0), fmaxf(a1v, o1));
        a0v = n0; a1v = n1;
    }
    const float gscore = a0v + a1v;

    float gsc[8];
    #pragma unroll
    for (int g = 0; g < 8; ++g) gsc[g] = __shfl(gscore, g << 3);

    const int g0 = lane >> 3;
    int myrank = 0;
    float v4 = -1e30f, v5 = -1e30f;
    #pragma unroll
    for (int h = 0; h < 8; ++h) {
        int rk = 0;
        #pragma unroll
        for (int h2 = 0; h2 < 8; ++h2)
            rk += ((gsc[h2] > gsc[h]) || (gsc[h2] == gsc[h] && h2 < h)) ? 1 : 0;
        if (h == g0) myrank = rk;
        if (rk == TOPKG - 1) v4 = gsc[h];
        if (rk == TOPKG)     v5 = gsc[h];
    }
    const bool sel = (myrank < TOPKG);
    const float margin_g = v4 - v5;

    float m0 = sel ? b0 : 0.f;
    float m1 = sel ? b1 : 0.f;
    float m2 = sel ? b2 : 0.f;
    float m3 = sel ? b3 : 0.f;

    float sum = 0.f;
    int myidx = 0; float mysc = 0.f;
    float prev = 0.f, mine = 1e30f;
    #pragma unroll
    for (int rr = 0; rr < TOPK + 1; ++rr) {
        float bv = m0; int bj = 0;
        if (m1 > bv) { bv = m1; bj = 1; }
        if (m2 > bv) { bv = m2; bj = 2; }
        if (m3 > bv) { bv = m3; bj = 3; }
        float bsc = (bj == 0) ? s0 : (bj == 1) ? s1 : (bj == 2) ? s2 : s3;
        int bidx = (lane << 2) | bj;
        #pragma unroll
        for (int off = 1; off < 64; off <<= 1) {
            float ov  = __shfl_xor(bv, off);
            int   oi  = __shfl_xor(bidx, off);
            float osc = __shfl_xor(bsc, off);
            if (ov > bv || (ov == bv && oi < bidx)) { bv = ov; bidx = oi; bsc = osc; }
        }
        if (rr) mine = fminf(mine, prev - bv);
        prev = bv;
        if (rr < TOPK) {
            sum += bsc;
            if (lane == rr) { myidx = bidx; mysc = bsc; }
            if ((bidx >> 2) == lane) {
                const int sl = bidx & 3;
                if      (sl == 0) m0 = -FLT_MAX;
                else if (sl == 1) m1 = -FLT_MAX;
                else if (sl == 2) m2 = -FLT_MAX;
                else              m3 = -FLT_MAX;
            }
        }
    }

    const bool fb = (margin_g < TAU_G) || (mine < TAU_E);
    if (fb) {
        if (lane == 0) { int p = atomicAdd(cnt, 1); if (p < MAXFB) list[p] = t; }
    } else if (lane < TOPK) {
        const size_t base = (size_t)t * TOPK + lane;
        out[base] = (float)myidx;
        out[(size_t)TOKENS * TOPK + base] = mysc / (sum + 1e-20f) * 2.5f;
    }
}

// ---------------- f1: exact f64 logits for flagged tokens (coalesced) ----------------
__global__ __launch_bounds__(256) void fallback_logits(const float* __restrict__ A,
                                                       const float* __restrict__ W,
                                                       const int* __restrict__ cnt,
                                                       const int* __restrict__ list,
                                                       double* __restrict__ lgs) {
    __shared__ float As[2][HIDDEN];   // 56KB
    const int n = min(*cnt, MAXFB);
    const int base = blockIdx.x * 2;
    if (base >= n) return;
    const int tid = threadIdx.x;
    const int t0 = list[base];
    const int t1 = (base + 1 < n) ? list[base + 1] : t0;

    const float4* a0g = (const float4*)(A + (size_t)t0 * HIDDEN);
    const float4* a1g = (const float4*)(A + (size_t)t1 * HIDDEN);
    for (int i = tid; i < HIDDEN / 4; i += 256) {
        ((float4*)As[0])[i] = a0g[i];
        ((float4*)As[1])[i] = a1g[i];
    }
    __syncthreads();

    const int lane = tid & 63, wv = tid >> 6;
    for (int ei = 0; ei < 64; ++ei) {
        const int e = wv * 64 + ei;
        const float* wr = W + (size_t)e * HIDDEN;
        double ac0 = 0.0, ac1 = 0.0;
        #pragma unroll 4
        for (int it = 0; it < HIDDEN / 256; ++it) {
            const int k = it * 256 + (lane << 2);
            const float4 w4 = *(const float4*)(wr + k);
            const float4 x0 = *(const float4*)&As[0][k];
            const float4 x1 = *(const float4*)&As[1][k];
            ac0 = fma((double)x0.x, (double)w4.x, ac0);
            ac0 = fma((double)x0.y, (double)w4.y, ac0);
            ac0 = fma((double)x0.z, (double)w4.z, ac0);
            ac0 = fma((double)x0.w, (double)w4.w, ac0);
            ac1 = fma((double)x1.x, (double)w4.x, ac1);
            ac1 = fma((double)x1.y, (double)w4.y, ac1);
            ac1 = fma((double)x1.z, (double)w4.z, ac1);
            ac1 = fma((double)x1.w, (double)w4.w, ac1);
        }
        #pragma unroll
        for (int off = 32; off; off >>= 1) {
            ac0 += __shfl_xor(ac0, off);
            ac1 += __shfl_xor(ac1, off);
        }
        if (lane == 0) {
            lgs[(size_t)base * EXPERTS + e] = ac0;
            if (base + 1 < n) lgs[(size_t)(base + 1) * EXPERTS + e] = ac1;
        }
    }
}

// ---------------- f2: exact f64 route for flagged tokens ----------------
__global__ __launch_bounds__(256) void fallback_route(const double* __restrict__ lgs,
                                                      const float* __restrict__ bias,
                                                      const int* __restrict__ cnt,
                                                      const int* __restrict__ list,
                                                      float* __restrict__ out) {
    const int n  = min(*cnt, MAXFB);
    const int ti = blockIdx.x * 4 + (threadIdx.x >> 6);
    if (ti >= n) return;
    const int lane = threadIdx.x & 63;
    const int t = list[ti];

    const double l0 = lgs[(size_t)ti * EXPERTS + (lane << 2)];
    const double l1 = lgs[(size_t)ti * EXPERTS + (lane << 2) + 1];
    const double l2 = lgs[(size_t)ti * EXPERTS + (lane << 2) + 2];
    const double l3 = lgs[(size_t)ti * EXPERTS + (lane << 2) + 3];
    const float4 bzf = *(const float4*)(bias + (lane << 2));

    const double s0 = 1.0 / (1.0 + exp(-l0));
    const double s1 = 1.0 / (1.0 + exp(-l1));
    const double s2 = 1.0 / (1.0 + exp(-l2));
    const double s3 = 1.0 / (1.0 + exp(-l3));
    const double b0 = s0 + (double)bzf.x, b1 = s1 + (double)bzf.y;
    const double b2 = s2 + (double)bzf.z, b3 = s3 + (double)bzf.w;

    double hi01 = fmax(b0, b1), lo01 = fmin(b0, b1);
    double hi23 = fmax(b2, b3), lo23 = fmin(b2, b3);
    double a0v = fmax(hi01, hi23);
    double a1v = fmax(fmin(hi01, hi23), fmax(lo01, lo23));
    #pragma unroll
    for (int off = 1; off < 8; off <<= 1) {
        double o0 = __shfl_xor(a0v, off);
        double o1 = __shfl_xor(a1v, off);
        double n0 = fmax(a0v, o0);
        double n1 = fmax(fmin(a0v, o0), fmax(a1v, o1));
        a0v = n0; a1v = n1;
    }
    const double gscore = a0v + a1v;
    double gsc[8];
    #pragma unroll
    for (int g = 0; g < 8; ++g) gsc[g] = __shfl(gscore, g << 3);
    const int g0 = lane >> 3;
    int rank = 0;
    #pragma unroll
    for (int h = 0; h < 8; ++h)
        rank += ((gsc[h] > gscore) || (gsc[h] == gscore && h < g0)) ? 1 : 0;
    const bool sel = (rank < TOPKG);

    double m0 = sel ? b0 : 0.0;
    double m1 = sel ? b1 : 0.0;
    double m2 = sel ? b2 : 0.0;
    double m3 = sel ? b3 : 0.0;

    double sum = 0.0;
    int myidx = 0; double mysc = 0.0;
    #pragma unroll
    for (int rr = 0; rr < TOPK; ++rr) {
        double bv = m0; int bj = 0;
        if (m1 > bv) { bv = m1; bj = 1; }
        if (m2 > bv) { bv = m2; bj = 2; }
        if (m3 > bv) { bv = m3; bj = 3; }
        double bsc = (bj == 0) ? s0 : (bj == 1) ? s1 : (bj == 2) ? s2 : s3;
        int bidx = (lane << 2) | bj;
        #pragma unroll
        for (int off = 1; off < 64; off <<= 1) {
            double ov  = __shfl_xor(bv, off);
            int    oi  = __shfl_xor(bidx, off);
            double osc = __shfl_xor(bsc, off);
            if (ov > bv || (ov == bv && oi < bidx)) { bv = ov; bidx = oi; bsc = osc; }
        }
        sum += bsc;
        if (lane == rr) { myidx = bidx; mysc = bsc; }
        if ((bidx >> 2) == lane) {
            const int sl = bidx & 3;
            if      (sl == 0) m0 = -DBL_MAX;
            else if (sl == 1) m1 = -DBL_MAX;
            else if (sl == 2) m2 = -DBL_MAX;
            else              m3 = -DBL_MAX;
        }
    }
    if (lane < TOPK) {
        const size_t base = (size_t)t * TOPK + lane;
        out[base] = (float)myidx;
        out[(size_t)TOKENS * TOPK + base] = (float)(mysc / (sum + 1e-20) * 2.5);
    }
}

extern "C" void kernel_launch(void* const* d_in, const int* in_sizes, int n_in,
                              void* d_out, int out_size, void* d_ws, size_t ws_size,
                              hipStream_t stream) {
    const float* hs   = (const float*)d_in[0];
    const float* wt   = (const float*)d_in[1];
    const float* bias = (const float*)d_in[2];
    float* out = (float*)d_out;
    char* ws = (char*)d_ws;

    const size_t LGSZ = (size_t)TOKENS * EXPERTS * 4;   // 8 MB
    const size_t WIMG = (size_t)WIMG_HALF * 2;          // 3.67 MB per half

    if (ws_size >= 2 * LGSZ + 131072 + 2 * WIMG) {
        // deterministic 2-partial path
        float*  part  = (float*)ws;                        // P0 | P1
        int*    cnt   = (int*)(ws + 2 * LGSZ);
        int*    list  = (int*)(ws + 2 * LGSZ + 256);
        ushort* wsh   = (ushort*)(ws + 2 * LGSZ + 131072);
        ushort* wsl   = (ushort*)(ws + 2 * LGSZ + 131072 + WIMG);
        double* lgs64 = (double*)ws;                       // overlays P0 after route

        split_w<<<WIMG_HALF / 256, 256, 0, stream>>>(wt, wsh, wsl, cnt);
        logits_mfma<false><<<256, 256, 0, stream>>>(hs, wsh, wsl, part);
        route_margin<true><<<TOKENS / 4, 256, 0, stream>>>(part, bias, out, cnt, list);
        fallback_logits<<<MAXFB / 2, 256, 0, stream>>>(hs, wt, cnt, list, lgs64);
        fallback_route<<<MAXFB / 4, 256, 0, stream>>>(lgs64, bias, cnt, list, out);
    } else {
        // atomic single-buffer path
        float*  logits = (float*)ws;
        int*    cnt    = (int*)(ws + LGSZ);
        int*    list   = (int*)(ws + LGSZ + 256);
        ushort* wsh    = (ushort*)(ws + LGSZ + 131072);
        ushort* wsl    = (ushort*)(ws + LGSZ + 131072 + WIMG);
        double* lgs64  = (double*)ws;

        hipMemsetAsync(logits, 0, LGSZ, stream);
        split_w<<<WIMG_HALF / 256, 256, 0, stream>>>(wt, wsh, wsl, cnt);
        logits_mfma<true><<<256, 256, 0, stream>>>(hs, wsh, wsl, logits);
        route_margin<false><<<TOKENS / 4, 256, 0, stream>>>(logits, bias, out, cnt, list);
        fallback_logits<<<MAXFB / 2, 256, 0, stream>>>(hs, wt, cnt, list, lgs64);
        fallback_route<<<MAXFB / 4, 256, 0, stream>>>(lgs64, bias, cnt, list, out);
    }
}

// Round 8
// 261.539 us; speedup vs baseline: 2.7819x; 1.5186x over previous
//
#include <hip/hip_runtime.h>
#include <float.h>
#include <math.h>

#define TOKENS 8192
#define EXPERTS 256
#define HIDDEN 7168
#define TOPK 8
#define TOPKG 4

#define BM 128
#define BN 256
#define BK 32
#define KSPLIT 4
#define KQ (HIDDEN / KSPLIT)     // 1792
#define NKTB (KQ / BK)           // 56 k-steps per block

#define TAU_E 6.0e-6f
#define TAU_G 1.2e-5f
#define MAXFB 1024

// ---- ws layouts (bytes) ----
// partial path: P0..P3 [0, 32M) | cnt 33554432 | list +256 | WH 33685504 | WL 37355520 (end ~41M)
// atomic  path: LG [0, 8M) | cnt 8388608 | list +256 | WH 8519680 | WL 12189696
#define WIMG_ELEMS 1835008   // ushorts per buffer: 448 kt16 * 8 cg * 512

typedef __attribute__((ext_vector_type(8))) short bf16x8;
typedef __attribute__((ext_vector_type(16))) float f32x16;

__device__ inline ushort bf16_rne(float x) {
    uint u = __float_as_uint(x);
    return (ushort)((u + 0x7FFFu + ((u >> 16) & 1u)) >> 16);
}
__device__ inline float bf16_tof(ushort h) { return __uint_as_float((uint)h << 16); }

#define CVTPK(lo, hi) ({ uint r_; asm("v_cvt_pk_bf16_f32 %0, %1, %2" : "=v"(r_) : "v"(lo), "v"(hi)); r_; })
__device__ inline float lo16f(uint u) { return __uint_as_float(u << 16); }
__device__ inline float hi16f(uint u) { return __uint_as_float(u & 0xFFFF0000u); }

// W image, 32x32-MFMA fragment order over the FULL expert dim:
// wh[((kt16*8)+cg)*512 + lane*8 + j] = bf16(W[cg*32+(lane&31)][kt16*16+(lane>>5)*8+j])
__global__ __launch_bounds__(256) void split_w(const float* __restrict__ W,
                                               ushort* __restrict__ wh,
                                               ushort* __restrict__ wl,
                                               int* __restrict__ cnt) {
    if (blockIdx.x == 0 && threadIdx.x == 0) *cnt = 0;
    const int tau  = blockIdx.x * 256 + threadIdx.x;   // [0, 1835008)
    const int j    = tau & 7;
    const int lane = (tau >> 3) & 63;
    const int cg   = (tau >> 9) & 7;
    const int kt16 = tau >> 12;
    const int col  = cg * 32 + (lane & 31);
    const int k    = kt16 * 16 + (lane >> 5) * 8 + j;
    const float w  = W[(size_t)col * HIDDEN + k];
    const ushort h = bf16_rne(w);
    const ushort l = bf16_rne(w - bf16_tof(h));
    wh[tau] = h;
    wl[tau] = l;
}

// ---------------- bf16-split 32x32 MFMA GEMM ----------------
// Grid 256 = 64 mb x 4 ks (b = mb*4+ks -> each XCD hosts ONE ks W-slice, 1.84MB L2).
// 512 threads, 8 waves (2 wm x 4 wn), wave tile 64x64. A via LDS dbuf (cvt_pk
// split in-kernel); W fragments direct from the pre-split L2 image.
template <bool ATOMIC>
__global__ __launch_bounds__(512, 2) void logits_mfma(const float* __restrict__ A,
                                                      const ushort* __restrict__ wh,
                                                      const ushort* __restrict__ wl,
                                                      float* __restrict__ dst) {
    __shared__ ushort Ah[2][BM * BK];   // 8KB per buf
    __shared__ ushort Al[2][BM * BK];

    const int b  = blockIdx.x;
    const int ks = b & 3;
    const int mb = b >> 2;
    const int row0 = mb * BM;

    const int t = threadIdx.x, lane = t & 63, wid = t >> 6;
    const int wm = wid >> 2, wn = wid & 3;

    // A staging: thread t -> row sr=t>>2, octet q=t&3 (8 floats)
    const int sr = t >> 2, q = t & 3;
    const float* Ap = A + (size_t)(row0 + sr) * HIDDEN + (size_t)ks * KQ + q * 8;
    const int sswz = ((sr >> 1) ^ (sr >> 3)) & 3;
    const int sidx = sr * 32 + ((q ^ sswz) << 3);

    // A fragment read indices [mi][kh]
    int fidx[2][2];
    #pragma unroll
    for (int mi = 0; mi < 2; ++mi) {
        const int r = wm * 64 + mi * 32 + (lane & 31);
        const int swz = ((r >> 1) ^ (r >> 3)) & 3;
        #pragma unroll
        for (int kh = 0; kh < 2; ++kh)
            fidx[mi][kh] = r * 32 + (((kh * 2 + (lane >> 5)) ^ swz) << 3);
    }

    const int wlanes = lane * 8;

    f32x16 acc[2][2];
    #pragma unroll
    for (int mi = 0; mi < 2; ++mi)
        #pragma unroll
        for (int n = 0; n < 2; ++n) acc[mi][n] = (f32x16)0.f;

    float4 aA0, aA1, aB0, aB1;
    bf16x8 wAh[2][2], wAl[2][2], wBh[2][2], wBl[2][2];   // [n][kh]

    #define WLOAD(DH, DL, KTL) do {                                            \
        const size_t wo = ((size_t)((ks * NKTB + (KTL)) * 16 + wn * 2)) * 512 + wlanes; \
        DH[0][0] = *(const bf16x8*)(wh + wo);                                  \
        DH[1][0] = *(const bf16x8*)(wh + wo + 512);                            \
        DH[0][1] = *(const bf16x8*)(wh + wo + 4096);                           \
        DH[1][1] = *(const bf16x8*)(wh + wo + 4608);                           \
        DL[0][0] = *(const bf16x8*)(wl + wo);                                  \
        DL[1][0] = *(const bf16x8*)(wl + wo + 512);                            \
        DL[0][1] = *(const bf16x8*)(wl + wo + 4096);                           \
        DL[1][1] = *(const bf16x8*)(wl + wo + 4608);                           \
    } while (0)

    #define STAGE(BB, R0, R1) do {                                             \
        uint h0 = CVTPK(R0.x, R0.y), h1 = CVTPK(R0.z, R0.w);                   \
        uint h2 = CVTPK(R1.x, R1.y), h3 = CVTPK(R1.z, R1.w);                   \
        float q0 = R0.x - lo16f(h0), q1 = R0.y - hi16f(h0);                    \
        float q2 = R0.z - lo16f(h1), q3 = R0.w - hi16f(h1);                    \
        float q4 = R1.x - lo16f(h2), q5 = R1.y - hi16f(h2);                    \
        float q6 = R1.z - lo16f(h3), q7 = R1.w - hi16f(h3);                    \
        uint l0 = CVTPK(q0, q1), l1 = CVTPK(q2, q3);                           \
        uint l2 = CVTPK(q4, q5), l3 = CVTPK(q6, q7);                           \
        *(uint4*)&Ah[BB][sidx] = make_uint4(h0, h1, h2, h3);                   \
        *(uint4*)&Al[BB][sidx] = make_uint4(l0, l1, l2, l3);                   \
    } while (0)

    #define ALOAD(R0, R1, KTL) do {                                            \
        const int ka = ((KTL) < NKTB ? (KTL) : NKTB - 1) * BK;                 \
        R0 = *(const float4*)(Ap + ka);                                        \
        R1 = *(const float4*)(Ap + ka + 4);                                    \
    } while (0)

    #define MF __builtin_amdgcn_mfma_f32_32x32x16_bf16

    #define ITER(KT, BB, X0, X1, WXH, WXL, WYH, WYL) do {                      \
        __syncthreads();                                                       \
        bf16x8 afh[2][2], afl[2][2];                                           \
        afh[0][0] = *(const bf16x8*)&Ah[BB][fidx[0][0]];                       \
        afh[0][1] = *(const bf16x8*)&Ah[BB][fidx[0][1]];                       \
        afh[1][0] = *(const bf16x8*)&Ah[BB][fidx[1][0]];                       \
        afh[1][1] = *(const bf16x8*)&Ah[BB][fidx[1][1]];                       \
        afl[0][0] = *(const bf16x8*)&Al[BB][fidx[0][0]];                       \
        afl[0][1] = *(const bf16x8*)&Al[BB][fidx[0][1]];                       \
        afl[1][0] = *(const bf16x8*)&Al[BB][fidx[1][0]];                       \
        afl[1][1] = *(const bf16x8*)&Al[BB][fidx[1][1]];                       \
        STAGE((BB) ^ 1, X0, X1);                                               \
        ALOAD(X0, X1, (KT) + 3);                                               \
        WLOAD(WYH, WYL, ((KT) + 1 < NKTB ? (KT) + 1 : NKTB - 1));              \
        acc[0][0] = MF(afh[0][0], WXH[0][0], acc[0][0], 0, 0, 0);              \
        acc[0][0] = MF(afl[0][0], WXH[0][0], acc[0][0], 0, 0, 0);              \
        acc[0][0] = MF(afh[0][0], WXL[0][0], acc[0][0], 0, 0, 0);              \
        acc[0][1] = MF(afh[0][0], WXH[1][0], acc[0][1], 0, 0, 0);              \
        acc[0][1] = MF(afl[0][0], WXH[1][0], acc[0][1], 0, 0, 0);              \
        acc[0][1] = MF(afh[0][0], WXL[1][0], acc[0][1], 0, 0, 0);              \
        acc[1][0] = MF(afh[1][0], WXH[0][0], acc[1][0], 0, 0, 0);              \
        acc[1][0] = MF(afl[1][0], WXH[0][0], acc[1][0], 0, 0, 0);              \
        acc[1][0] = MF(afh[1][0], WXL[0][0], acc[1][0], 0, 0, 0);              \
        acc[1][1] = MF(afh[1][0], WXH[1][0], acc[1][1], 0, 0, 0);              \
        acc[1][1] = MF(afl[1][0], WXH[1][0], acc[1][1], 0, 0, 0);              \
        acc[1][1] = MF(afh[1][0], WXL[1][0], acc[1][1], 0, 0, 0);              \
        acc[0][0] = MF(afh[0][1], WXH[0][1], acc[0][0], 0, 0, 0);              \
        acc[0][0] = MF(afl[0][1], WXH[0][1], acc[0][0], 0, 0, 0);              \
        acc[0][0] = MF(afh[0][1], WXL[0][1], acc[0][0], 0, 0, 0);              \
        acc[0][1] = MF(afh[0][1], WXH[1][1], acc[0][1], 0, 0, 0);              \
        acc[0][1] = MF(afl[0][1], WXH[1][1], acc[0][1], 0, 0, 0);              \
        acc[0][1] = MF(afh[0][1], WXL[1][1], acc[0][1], 0, 0, 0);              \
        acc[1][0] = MF(afh[1][1], WXH[0][1], acc[1][0], 0, 0, 0);              \
        acc[1][0] = MF(afl[1][1], WXH[0][1], acc[1][0], 0, 0, 0);              \
        acc[1][0] = MF(afh[1][1], WXL[0][1], acc[1][0], 0, 0, 0);              \
        acc[1][1] = MF(afh[1][1], WXH[1][1], acc[1][1], 0, 0, 0);              \
        acc[1][1] = MF(afl[1][1], WXH[1][1], acc[1][1], 0, 0, 0);              \
        acc[1][1] = MF(afh[1][1], WXL[1][1], acc[1][1], 0, 0, 0);              \
    } while (0)

    // prologue
    ALOAD(aA0, aA1, 0);
    STAGE(0, aA0, aA1);
    ALOAD(aA0, aA1, 1);
    ALOAD(aB0, aB1, 2);
    WLOAD(wAh, wAl, 0);

    for (int kt2 = 0; kt2 < NKTB; kt2 += 2) {
        ITER(kt2,     0, aA0, aA1, wAh, wAl, wBh, wBl);
        ITER(kt2 + 1, 1, aB0, aB1, wBh, wBl, wAh, wAl);
    }

    // epilogue: C/D col=lane&31, row=(g&3)+8*(g>>2)+4*(lane>>5)  [m74/m101]
    float* o = ATOMIC ? dst : dst + (size_t)ks * TOKENS * EXPERTS;
    #pragma unroll
    for (int mi = 0; mi < 2; ++mi)
        #pragma unroll
        for (int n = 0; n < 2; ++n)
            #pragma unroll
            for (int g = 0; g < 16; ++g) {
                const int row = row0 + wm * 64 + mi * 32 + (g & 3) + ((g >> 2) << 3) + ((lane >> 5) << 2);
                const int col = wn * 64 + n * 32 + (lane & 31);
                const size_t idx = (size_t)row * EXPERTS + col;
                if (ATOMIC) atomicAdd(o + idx, acc[mi][n][g]);
                else        o[idx] = acc[mi][n][g];
            }
    #undef ITER
    #undef MF
    #undef ALOAD
    #undef STAGE
    #undef WLOAD
}

// ---------------- fast route with decision margins ----------------
template <int NPART>
__global__ __launch_bounds__(256) void route_margin(const float* __restrict__ p0,
                                                    const float* __restrict__ bias,
                                                    float* __restrict__ out,
                                                    int* __restrict__ cnt,
                                                    int* __restrict__ list) {
    const int lane = threadIdx.x & 63;
    const int t    = blockIdx.x * 4 + (threadIdx.x >> 6);

    float4 lg = *(const float4*)(p0 + (size_t)t * EXPERTS + (lane << 2));
    #pragma unroll
    for (int p = 1; p < NPART; ++p) {
        const float4 l2 = *(const float4*)(p0 + (size_t)p * TOKENS * EXPERTS +
                                           (size_t)t * EXPERTS + (lane << 2));
        lg.x += l2.x; lg.y += l2.y; lg.z += l2.z; lg.w += l2.w;
    }
    const float4 bz = *(const float4*)(bias + (lane << 2));

    const float s0 = 1.f / (1.f + expf(-lg.x));
    const float s1 = 1.f / (1.f + expf(-lg.y));
    const float s2 = 1.f / (1.f + expf(-lg.z));
    const float s3 = 1.f / (1.f + expf(-lg.w));
    const float b0 = s0 + bz.x, b1 = s1 + bz.y, b2 = s2 + bz.z, b3 = s3 + bz.w;

    float hi01 = fmaxf(b0, b1), lo01 = fminf(b0, b1);
    float hi23 = fmaxf(b2, b3), lo23 = fminf(b2, b3);
    float a0v = fmaxf(hi01, hi23);
    float a1v = fmaxf(fminf(hi01, hi23), fmaxf(lo01, lo23));
    #pragma unroll
    for (int off = 1; off < 8; off <<= 1) {
        float o0 = __shfl_xor(a0v, off);
        float o1 = __shfl_xor(a1v, off);
        float n0 = fmaxf(a0v, o0);
        float n1 = fmaxf(fminf(a0v, o0), fmaxf(a1v, o1));
        a0v = n0; a1v = n1;
    }
    const float gscore = a0v + a1v;

    float gsc[8];
    #pragma unroll
    for (int g = 0; g < 8; ++g) gsc[g] = __shfl(gscore, g << 3);

    const int g0 = lane >> 3;
    int myrank = 0;
    float v4 = -1e30f, v5 = -1e30f;
    #pragma unroll
    for (int h = 0; h < 8; ++h) {
        int rk = 0;
        #pragma unroll
        for (int h2 = 0; h2 < 8; ++h2)
            rk += ((gsc[h2] > gsc[h]) || (gsc[h2] == gsc[h] && h2 < h)) ? 1 : 0;
        if (h == g0) myrank = rk;
        if (rk == TOPKG - 1) v4 = gsc[h];
        if (rk == TOPKG)     v5 = gsc[h];
    }
    const bool sel = (myrank < TOPKG);
    const float margin_g = v4 - v5;

    float m0 = sel ? b0 : 0.f;
    float m1 = sel ? b1 : 0.f;
    float m2 = sel ? b2 : 0.f;
    float m3 = sel ? b3 : 0.f;

    float sum = 0.f;
    int myidx = 0; float mysc = 0.f;
    float prev = 0.f, mine = 1e30f;
    #pragma unroll
    for (int rr = 0; rr < TOPK + 1; ++rr) {
        float bv = m0; int bj = 0;
        if (m1 > bv) { bv = m1; bj = 1; }
        if (m2 > bv) { bv = m2; bj = 2; }
        if (m3 > bv) { bv = m3; bj = 3; }
        float bsc = (bj == 0) ? s0 : (bj == 1) ? s1 : (bj == 2) ? s2 : s3;
        int bidx = (lane << 2) | bj;
        #pragma unroll
        for (int off = 1; off < 64; off <<= 1) {
            float ov  = __shfl_xor(bv, off);
            int   oi  = __shfl_xor(bidx, off);
            float osc = __shfl_xor(bsc, off);
            if (ov > bv || (ov == bv && oi < bidx)) { bv = ov; bidx = oi; bsc = osc; }
        }
        if (rr) mine = fminf(mine, prev - bv);
        prev = bv;
        if (rr < TOPK) {
            sum += bsc;
            if (lane == rr) { myidx = bidx; mysc = bsc; }
            if ((bidx >> 2) == lane) {
                const int sl = bidx & 3;
                if      (sl == 0) m0 = -FLT_MAX;
                else if (sl == 1) m1 = -FLT_MAX;
                else if (sl == 2) m2 = -FLT_MAX;
                else              m3 = -FLT_MAX;
            }
        }
    }

    const bool fb = (margin_g < TAU_G) || (mine < TAU_E);
    if (fb) {
        if (lane == 0) { int p = atomicAdd(cnt, 1); if (p < MAXFB) list[p] = t; }
    } else if (lane < TOPK) {
        const size_t base = (size_t)t * TOPK + lane;
        out[base] = (float)myidx;
        out[(size_t)TOKENS * TOPK + base] = mysc / (sum + 1e-20f) * 2.5f;
    }
}

// ---------------- f1: exact f64 logits for flagged tokens ----------------
// 512 threads, 2 tokens/block; wave wv owns experts wv*32+ei; coalesced W reads.
__global__ __launch_bounds__(512) void fallback_logits(const float* __restrict__ A,
                                                       const float* __restrict__ W,
                                                       const int* __restrict__ cnt,
                                                       const int* __restrict__ list,
                                                       double* __restrict__ lgs) {
    __shared__ float As[2][HIDDEN];   // 56KB
    const int n = min(*cnt, MAXFB);
    const int base = blockIdx.x * 2;
    if (base >= n) return;
    const int tid = threadIdx.x;
    const int t0 = list[base];
    const int t1 = (base + 1 < n) ? list[base + 1] : t0;

    const float4* a0g = (const float4*)(A + (size_t)t0 * HIDDEN);
    const float4* a1g = (const float4*)(A + (size_t)t1 * HIDDEN);
    for (int i = tid; i < HIDDEN / 4; i += 512) {
        ((float4*)As[0])[i] = a0g[i];
        ((float4*)As[1])[i] = a1g[i];
    }
    __syncthreads();

    const int lane = tid & 63, wv = tid >> 6;
    for (int ei = 0; ei < 32; ++ei) {
        const int e = wv * 32 + ei;
        const float* wr = W + (size_t)e * HIDDEN;
        double ac0 = 0.0, ac1 = 0.0;
        #pragma unroll 4
        for (int it = 0; it < HIDDEN / 256; ++it) {   // 28 iterations
            const int k = it * 256 + (lane << 2);
            const float4 w4 = *(const float4*)(wr + k);
            const float4 x0 = *(const float4*)&As[0][k];
            const float4 x1 = *(const float4*)&As[1][k];
            ac0 = fma((double)x0.x, (double)w4.x, ac0);
            ac0 = fma((double)x0.y, (double)w4.y, ac0);
            ac0 = fma((double)x0.z, (double)w4.z, ac0);
            ac0 = fma((double)x0.w, (double)w4.w, ac0);
            ac1 = fma((double)x1.x, (double)w4.x, ac1);
            ac1 = fma((double)x1.y, (double)w4.y, ac1);
            ac1 = fma((double)x1.z, (double)w4.z, ac1);
            ac1 = fma((double)x1.w, (double)w4.w, ac1);
        }
        #pragma unroll
        for (int off = 32; off; off >>= 1) {
            ac0 += __shfl_xor(ac0, off);
            ac1 += __shfl_xor(ac1, off);
        }
        if (lane == 0) {
            lgs[(size_t)base * EXPERTS + e] = ac0;
            if (base + 1 < n) lgs[(size_t)(base + 1) * EXPERTS + e] = ac1;
        }
    }
}

// ---------------- f2: exact f64 route for flagged tokens ----------------
__global__ __launch_bounds__(256) void fallback_route(const double* __restrict__ lgs,
                                                      const float* __restrict__ bias,
                                                      const int* __restrict__ cnt,
                                                      const int* __restrict__ list,
                                                      float* __restrict__ out) {
    const int n  = min(*cnt, MAXFB);
    const int ti = blockIdx.x * 4 + (threadIdx.x >> 6);
    if (ti >= n) return;
    const int lane = threadIdx.x & 63;
    const int t = list[ti];

    const double l0 = lgs[(size_t)ti * EXPERTS + (lane << 2)];
    const double l1 = lgs[(size_t)ti * EXPERTS + (lane << 2) + 1];
    const double l2 = lgs[(size_t)ti * EXPERTS + (lane << 2) + 2];
    const double l3 = lgs[(size_t)ti * EXPERTS + (lane << 2) + 3];
    const float4 bzf = *(const float4*)(bias + (lane << 2));

    const double s0 = 1.0 / (1.0 + exp(-l0));
    const double s1 = 1.0 / (1.0 + exp(-l1));
    const double s2 = 1.0 / (1.0 + exp(-l2));
    const double s3 = 1.0 / (1.0 + exp(-l3));
    const double b0 = s0 + (double)bzf.x, b1 = s1 + (double)bzf.y;
    const double b2 = s2 + (double)bzf.z, b3 = s3 + (double)bzf.w;

    double hi01 = fmax(b0, b1), lo01 = fmin(b0, b1);
    double hi23 = fmax(b2, b3), lo23 = fmin(b2, b3);
    double a0v = fmax(hi01, hi23);
    double a1v = fmax(fmin(hi01, hi23), fmax(lo01, lo23));
    #pragma unroll
    for (int off = 1; off < 8; off <<= 1) {
        double o0 = __shfl_xor(a0v, off);
        double o1 = __shfl_xor(a1v, off);
        double n0 = fmax(a0v, o0);
        double n1 = fmax(fmin(a0v, o0), fmax(a1v, o1));
        a0v = n0; a1v = n1;
    }
    const double gscore = a0v + a1v;
    double gsc[8];
    #pragma unroll
    for (int g = 0; g < 8; ++g) gsc[g] = __shfl(gscore, g << 3);
    const int g0 = lane >> 3;
    int rank = 0;
    #pragma unroll
    for (int h = 0; h < 8; ++h)
        rank += ((gsc[h] > gscore) || (gsc[h] == gscore && h < g0)) ? 1 : 0;
    const bool sel = (rank < TOPKG);

    double m0 = sel ? b0 : 0.0;
    double m1 = sel ? b1 : 0.0;
    double m2 = sel ? b2 : 0.0;
    double m3 = sel ? b3 : 0.0;

    double sum = 0.0;
    int myidx = 0; double mysc = 0.0;
    #pragma unroll
    for (int rr = 0; rr < TOPK; ++rr) {
        double bv = m0; int bj = 0;
        if (m1 > bv) { bv = m1; bj = 1; }
        if (m2 > bv) { bv = m2; bj = 2; }
        if (m3 > bv) { bv = m3; bj = 3; }
        double bsc = (bj == 0) ? s0 : (bj == 1) ? s1 : (bj == 2) ? s2 : s3;
        int bidx = (lane << 2) | bj;
        #pragma unroll
        for (int off = 1; off < 64; off <<= 1) {
            double ov  = __shfl_xor(bv, off);
            int    oi  = __shfl_xor(bidx, off);
            double osc = __shfl_xor(bsc, off);
            if (ov > bv || (ov == bv && oi < bidx)) { bv = ov; bidx = oi; bsc = osc; }
        }
        sum += bsc;
        if (lane == rr) { myidx = bidx; mysc = bsc; }
        if ((bidx >> 2) == lane) {
            const int sl = bidx & 3;
            if      (sl == 0) m0 = -DBL_MAX;
            else if (sl == 1) m1 = -DBL_MAX;
            else if (sl == 2) m2 = -DBL_MAX;
            else              m3 = -DBL_MAX;
        }
    }
    if (lane < TOPK) {
        const size_t base = (size_t)t * TOPK + lane;
        out[base] = (float)myidx;
        out[(size_t)TOKENS * TOPK + base] = (float)(mysc / (sum + 1e-20) * 2.5);
    }
}

extern "C" void kernel_launch(void* const* d_in, const int* in_sizes, int n_in,
                              void* d_out, int out_size, void* d_ws, size_t ws_size,
                              hipStream_t stream) {
    const float* hs   = (const float*)d_in[0];
    const float* wt   = (const float*)d_in[1];
    const float* bias = (const float*)d_in[2];
    float* out = (float*)d_out;
    char* ws = (char*)d_ws;

    const size_t LGSZ = (size_t)TOKENS * EXPERTS * 4;     // 8 MB
    const size_t WIMG = (size_t)WIMG_ELEMS * 2;           // 3.67 MB per buffer

    if (ws_size >= KSPLIT * LGSZ + 131072 + 2 * WIMG) {
        // deterministic 4-partial path
        float*  part  = (float*)ws;
        int*    cnt   = (int*)(ws + KSPLIT * LGSZ);
        int*    list  = (int*)(ws + KSPLIT * LGSZ + 256);
        ushort* wsh   = (ushort*)(ws + KSPLIT * LGSZ + 131072);
        ushort* wsl   = (ushort*)(ws + KSPLIT * LGSZ + 131072 + WIMG);
        double* lgs64 = (double*)ws;   // overlays P0 after route

        split_w<<<WIMG_ELEMS / 256, 256, 0, stream>>>(wt, wsh, wsl, cnt);
        logits_mfma<false><<<256, 512, 0, stream>>>(hs, wsh, wsl, part);
        route_margin<KSPLIT><<<TOKENS / 4, 256, 0, stream>>>(part, bias, out, cnt, list);
        fallback_logits<<<MAXFB / 2, 512, 0, stream>>>(hs, wt, cnt, list, lgs64);
        fallback_route<<<MAXFB / 4, 256, 0, stream>>>(lgs64, bias, cnt, list, out);
    } else {
        // atomic single-buffer path
        float*  logits = (float*)ws;
        int*    cnt    = (int*)(ws + LGSZ);
        int*    list   = (int*)(ws + LGSZ + 256);
        ushort* wsh    = (ushort*)(ws + LGSZ + 131072);
        ushort* wsl    = (ushort*)(ws + LGSZ + 131072 + WIMG);
        double* lgs64  = (double*)ws;

        hipMemsetAsync(logits, 0, LGSZ, stream);
        split_w<<<WIMG_ELEMS / 256, 256, 0, stream>>>(wt, wsh, wsl, cnt);
        logits_mfma<true><<<256, 512, 0, stream>>>(hs, wsh, wsl, logits);
        route_margin<1><<<TOKENS / 4, 256, 0, stream>>>(logits, bias, out, cnt, list);
        fallback_logits<<<MAXFB / 2, 512, 0, stream>>>(hs, wt, cnt, list, lgs64);
        fallback_route<<<MAXFB / 4, 256, 0, stream>>>(lgs64, bias, cnt, list, out);
    }
}